// Round 14
// baseline (1821.345 us; speedup 1.0000x reference)
//
#include <hip/hip_runtime.h>

typedef __attribute__((ext_vector_type(8))) short short8;
typedef __attribute__((ext_vector_type(4))) float f32x4;

__device__ __forceinline__ float4 ld4(const float* p){ return *reinterpret_cast<const float4*>(p); }
__device__ __forceinline__ void st4(float* p, const float4& v){ *reinterpret_cast<float4*>(p) = v; }

__device__ __forceinline__ unsigned short f2b(float x){
  unsigned int u = __float_as_uint(x);
  unsigned int r = (u + 0x7fffu + ((u >> 16) & 1u)) >> 16;
  return (unsigned short)r;
}
__device__ __forceinline__ float b2f(unsigned short b){
  return __uint_as_float(((unsigned int)b) << 16);
}

__device__ __forceinline__ float fsigmoid(float x){ return 1.f / (1.f + __expf(-x)); }
__device__ __forceinline__ float ftanh(float x){ return 1.f - 2.f / (1.f + __expf(2.f * x)); }

__device__ __forceinline__ short8 cvt_frag(float4 f0, float4 f1){
  short8 a;
  a[0]=(short)f2b(f0.x); a[1]=(short)f2b(f0.y); a[2]=(short)f2b(f0.z); a[3]=(short)f2b(f0.w);
  a[4]=(short)f2b(f1.x); a[5]=(short)f2b(f1.y); a[6]=(short)f2b(f1.z); a[7]=(short)f2b(f1.w);
  return a;
}

// ============ weight fragmentization ============
__global__ void build_frag_kmajor(const float* __restrict__ B, int ldb,
                                  unsigned short* __restrict__ BF, int KB, int CTG)
{
  int idx = blockIdx.x * 256 + threadIdx.x;
  int total = KB * CTG * 512;
  if (idx >= total) return;
  int j = idx & 7, lane = (idx >> 3) & 63, rest = idx >> 9;
  int ctg = rest % CTG, kb = rest / CTG;
  int k = kb * 32 + ((lane >> 4) << 3) + j;
  int col = ctg * 16 + (lane & 15);
  BF[idx] = f2b(B[(size_t)k * ldb + col]);
}

// LSTM wave-slice layout (8 waves x 16 j-cols each), round-5 layout
__global__ void build_frag_lstm3(const float* __restrict__ Wih, const float* __restrict__ Whh,
                                 unsigned short* __restrict__ BF)
{
  int idx = blockIdx.x * 256 + threadIdx.x;
  if (idx >= 131072) return;
  int j = idx & 7, lane = (idx >> 3) & 63;
  int g = (idx >> 9) & 3, kb = (idx >> 11) & 7, w = idx >> 14;
  int col = g * 128 + w * 16 + (lane & 15);
  int k = kb * 32 + ((lane >> 4) << 3) + j;
  float v = (k < 128) ? Wih[(size_t)col * 128 + k] : Whh[(size_t)col * 128 + (k - 128)];
  BF[idx] = f2b(v);
}

// ============ generic MFMA GEMM ============
template<int CT, int KB, int OUTBF, int RELU, int ABF16>
__global__ __launch_bounds__(256)
void gemm_mfma(const void* __restrict__ Av, int lda,
               const unsigned short* __restrict__ BF, int ctgTot,
               float* __restrict__ Cf, unsigned short* __restrict__ Cb, int ldc,
               const float* __restrict__ bias, int nrows)
{
  const int tid = threadIdx.x, lane = tid & 63, wid = tid >> 6;
  const int row0 = blockIdx.x * 64 + wid * 16;
  const int cg = blockIdx.y * CT;
  const int r = row0 + (lane & 15);
  const bool rok = r < nrows;
  const int koff = (lane >> 4) << 3;

  f32x4 acc[CT];
#pragma unroll
  for (int ct = 0; ct < CT; ++ct) {
    float b = bias ? bias[(cg + ct) * 16 + (lane & 15)] : 0.f;
    acc[ct] = (f32x4){b, b, b, b};
  }

#pragma unroll
  for (int kb = 0; kb < KB; ++kb) {
    short8 a = {};
    if (rok) {
      if (ABF16) {
        a = *(const short8*)((const unsigned short*)Av + (size_t)r * lda + kb * 32 + koff);
      } else {
        const float* p = (const float*)Av + (size_t)r * lda + kb * 32 + koff;
        a = cvt_frag(ld4(p), ld4(p + 4));
      }
    }
#pragma unroll
    for (int ct = 0; ct < CT; ++ct) {
      const short8 b = *(const short8*)(BF + ((size_t)(kb * ctgTot + cg + ct) * 64 + lane) * 8);
      acc[ct] = __builtin_amdgcn_mfma_f32_16x16x32_bf16(a, b, acc[ct], 0, 0, 0);
    }
  }

  const int orow = row0 + ((lane >> 4) << 2);
#pragma unroll
  for (int ct = 0; ct < CT; ++ct) {
    int col = (cg + ct) * 16 + (lane & 15);
#pragma unroll
    for (int rg = 0; rg < 4; ++rg) {
      int rr = orow + rg;
      if (rr >= nrows) continue;
      float v = acc[ct][rg];
      if (RELU) v = fmaxf(v, 0.f);
      if (OUTBF) Cb[(size_t)rr * ldc + col] = f2b(v);
      else       Cf[(size_t)rr * ldc + col] = v;
    }
  }
}

// ============ fully fused 2-layer x T=3 LSTM (r12 structure + grid-stride tiles) ============
__global__ __launch_bounds__(512, 2)
void lstm_fused(const unsigned short* __restrict__ tempb,
                const unsigned short* __restrict__ L0F, const unsigned short* __restrict__ L1F,
                const float* __restrict__ bih0, const float* __restrict__ bhh0,
                const float* __restrict__ bih1, const float* __restrict__ bhh1,
                float* __restrict__ temporal, float* __restrict__ hlast, int nrows)
{
  __shared__ unsigned short h0b[8192];
  __shared__ unsigned short h1b[8192];
  __shared__ float h1f[64 * 132];
  const int tid = threadIdx.x, lane = tid & 63, w = tid >> 6;
  const int rbase = lane & 15;
  const int koff = (lane >> 4) << 3;
  const int c15 = lane & 15;
  const int jw = w * 16;

  float bs0[4], bs1[4];
#pragma unroll
  for (int g = 0; g < 4; ++g) {
    int col = g * 128 + jw + c15;
    bs0[g] = bih0[col] + bhh0[col];
    bs1[g] = bih1[col] + bhh1[col];
  }

  const unsigned short* BF0 = L0F + (size_t)w * 16384;
  const unsigned short* BF1 = L1F + (size_t)w * 16384;

  const int T = (nrows + 63) >> 6;
  for (int tile = blockIdx.x; tile < T; tile += gridDim.x) {
    const int row0 = tile * 64;

    f32x4 c0[4], c1[4];
#pragma unroll
    for (int i = 0; i < 4; ++i) { c0[i] = (f32x4){0,0,0,0}; c1[i] = (f32x4){0,0,0,0}; }

    f32x4 acc[4][4];

    for (int t = 0; t < 3; ++t) {
      // ---------- layer 0 ----------
#pragma unroll
      for (int rf = 0; rf < 4; ++rf)
#pragma unroll
        for (int g = 0; g < 4; ++g) acc[rf][g] = (f32x4){bs0[g], bs0[g], bs0[g], bs0[g]};

#pragma unroll
      for (int kb = 0; kb < 4; ++kb) {
        short8 a[4];
#pragma unroll
        for (int rf = 0; rf < 4; ++rf) {
          int r = row0 + rf * 16 + rbase;
          a[rf] = (r < nrows) ? *(const short8*)(tempb + (size_t)r * 384 + t * 128 + kb * 32 + koff)
                              : (short8){0,0,0,0,0,0,0,0};
        }
#pragma unroll
        for (int g = 0; g < 4; ++g) {
          const short8 b = *(const short8*)(BF0 + (((size_t)kb * 4 + g) * 64 + lane) * 8);
#pragma unroll
          for (int rf = 0; rf < 4; ++rf)
            acc[rf][g] = __builtin_amdgcn_mfma_f32_16x16x32_bf16(a[rf], b, acc[rf][g], 0, 0, 0);
        }
      }
      if (t > 0) {
#pragma unroll
        for (int kb = 4; kb < 8; ++kb) {
          short8 a[4];
#pragma unroll
          for (int rf = 0; rf < 4; ++rf) {
            int rl = rf * 16 + rbase;
            int kk = (kb - 4) * 32 + koff;
            a[rf] = *(const short8*)(h0b + rl * 128 + (kk ^ ((rl & 7) << 3)));
          }
#pragma unroll
          for (int g = 0; g < 4; ++g) {
            const short8 b = *(const short8*)(BF0 + (((size_t)kb * 4 + g) * 64 + lane) * 8);
#pragma unroll
            for (int rf = 0; rf < 4; ++rf)
              acc[rf][g] = __builtin_amdgcn_mfma_f32_16x16x32_bf16(a[rf], b, acc[rf][g], 0, 0, 0);
          }
        }
      }

      __syncthreads();  // A

#pragma unroll
      for (int rf = 0; rf < 4; ++rf) {
        int j = jw + c15;
#pragma unroll
        for (int rg = 0; rg < 4; ++rg) {
          float si = fsigmoid(acc[rf][0][rg]);
          float sf = fsigmoid(acc[rf][1][rg]);
          float gg = ftanh(acc[rf][2][rg]);
          float so = fsigmoid(acc[rf][3][rg]);
          float c = sf * c0[rf][rg] + si * gg;
          c0[rf][rg] = c;
          float hh = so * ftanh(c);
          int rl = rf * 16 + ((lane >> 4) << 2) + rg;
          h0b[rl * 128 + (j ^ ((rl & 7) << 3))] = f2b(hh);
        }
      }

      __syncthreads();  // B

      // ---------- layer 1 ----------
#pragma unroll
      for (int rf = 0; rf < 4; ++rf)
#pragma unroll
        for (int g = 0; g < 4; ++g) acc[rf][g] = (f32x4){bs1[g], bs1[g], bs1[g], bs1[g]};

#pragma unroll
      for (int kb = 0; kb < 4; ++kb) {
        short8 a[4];
#pragma unroll
        for (int rf = 0; rf < 4; ++rf) {
          int rl = rf * 16 + rbase;
          int kk = kb * 32 + koff;
          a[rf] = *(const short8*)(h0b + rl * 128 + (kk ^ ((rl & 7) << 3)));
        }
#pragma unroll
        for (int g = 0; g < 4; ++g) {
          const short8 b = *(const short8*)(BF1 + (((size_t)kb * 4 + g) * 64 + lane) * 8);
#pragma unroll
          for (int rf = 0; rf < 4; ++rf)
            acc[rf][g] = __builtin_amdgcn_mfma_f32_16x16x32_bf16(a[rf], b, acc[rf][g], 0, 0, 0);
        }
      }
      if (t > 0) {
#pragma unroll
        for (int kb = 4; kb < 8; ++kb) {
          short8 a[4];
#pragma unroll
          for (int rf = 0; rf < 4; ++rf) {
            int rl = rf * 16 + rbase;
            int kk = (kb - 4) * 32 + koff;
            a[rf] = *(const short8*)(h1b + rl * 128 + (kk ^ ((rl & 7) << 3)));
          }
#pragma unroll
          for (int g = 0; g < 4; ++g) {
            const short8 b = *(const short8*)(BF1 + (((size_t)kb * 4 + g) * 64 + lane) * 8);
#pragma unroll
            for (int rf = 0; rf < 4; ++rf)
              acc[rf][g] = __builtin_amdgcn_mfma_f32_16x16x32_bf16(a[rf], b, acc[rf][g], 0, 0, 0);
          }
        }
      }

      __syncthreads();  // C

#pragma unroll
      for (int rf = 0; rf < 4; ++rf) {
        int j = jw + c15;
#pragma unroll
        for (int rg = 0; rg < 4; ++rg) {
          float si = fsigmoid(acc[rf][0][rg]);
          float sf = fsigmoid(acc[rf][1][rg]);
          float gg = ftanh(acc[rf][2][rg]);
          float so = fsigmoid(acc[rf][3][rg]);
          float c = sf * c1[rf][rg] + si * gg;
          c1[rf][rg] = c;
          float hh = so * ftanh(c);
          int rl = rf * 16 + ((lane >> 4) << 2) + rg;
          h1b[rl * 128 + (j ^ ((rl & 7) << 3))] = f2b(hh);
          h1f[rl * 132 + j] = hh;
        }
      }

      __syncthreads();  // D

#pragma unroll
      for (int k = 0; k < 4; ++k) {
        int idx = tid + k * 512;
        int row = idx >> 5;
        int c4 = (idx & 31) << 2;
        int r = row0 + row;
        if (r < nrows) {
          float4 v = ld4(&h1f[row * 132 + c4]);
          st4(&temporal[(size_t)r * 384 + t * 128 + c4], v);
          if (t == 2) st4(&hlast[(size_t)r * 128 + c4], v);
        }
      }
    }
    __syncthreads();  // E: tile boundary (copy-out reads done before next tile's writes)
  }
}

// ============ encoder tail ============
__global__ void encoder_finish_kernel(const float* __restrict__ pre, const float* __restrict__ itype,
                                      const float* __restrict__ mask, const float* __restrict__ Wenc,
                                      const float* __restrict__ benc, unsigned short* __restrict__ hb, int n)
{
  int idx = blockIdx.x * blockDim.x + threadIdx.x;
  if (idx >= n * 128) return;
  int nn = idx >> 7, j = idx & 127;
  float v = pre[idx]
          + itype[nn * 3 + 0] * Wenc[128 * 128 + j]
          + itype[nn * 3 + 1] * Wenc[129 * 128 + j]
          + itype[nn * 3 + 2] * Wenc[130 * 128 + j]
          + benc[j];
  hb[idx] = f2b(fmaxf(v, 0.f) * mask[nn]);
}

// ============ CSR build ============
__global__ void count_kernel(const int* __restrict__ dst, int* __restrict__ cnt, int E, int EP)
{
  int e = blockIdx.x * blockDim.x + threadIdx.x;
  if (e >= EP) return;
  int d = (e < E) ? dst[e] : (e - E);
  atomicAdd(&cnt[d], 1);
}

__global__ __launch_bounds__(1024)
void scan1_kernel(const int* __restrict__ cnt, int* __restrict__ indptr,
                  int* __restrict__ bsum, int n)
{
  __shared__ int wsum[16];
  int tid = threadIdx.x;
  int lane = tid & 63, wv = tid >> 6;
  int idx = blockIdx.x * 1024 + tid;
  int v = (idx < n) ? cnt[idx] : 0;
  int x = v;
#pragma unroll
  for (int off = 1; off < 64; off <<= 1) { int y = __shfl_up(x, off); if (lane >= off) x += y; }
  if (lane == 63) wsum[wv] = x;
  __syncthreads();
  if (wv == 0) {
    int t = (lane < 16) ? wsum[lane] : 0;
#pragma unroll
    for (int off = 1; off < 16; off <<= 1) { int y = __shfl_up(t, off); if (lane >= off) t += y; }
    if (lane < 16) wsum[lane] = t;
  }
  __syncthreads();
  int offs = wv ? wsum[wv - 1] : 0;
  if (idx < n) indptr[idx] = offs + x - v;
  if (tid == 0) bsum[blockIdx.x] = wsum[15];
}

__global__ void scan2_kernel(int* __restrict__ bsum, int* __restrict__ indptr, int nb, int n)
{
  if (threadIdx.x == 0 && blockIdx.x == 0) {
    int run = 0;
    for (int i = 0; i < nb; ++i) { int t = bsum[i]; bsum[i] = run; run += t; }
    indptr[n] = run;
  }
}

__global__ __launch_bounds__(1024)
void scan3_kernel(int* __restrict__ indptr, const int* __restrict__ bsum, int n)
{
  int idx = blockIdx.x * 1024 + threadIdx.x;
  if (idx < n) indptr[idx] += bsum[blockIdx.x];
}

__global__ void fill_kernel(const int* __restrict__ src, const int* __restrict__ dst,
                            const int* __restrict__ indptr, int* __restrict__ fillc,
                            int* __restrict__ srcl, int E, int EP)
{
  int e = blockIdx.x * blockDim.x + threadIdx.x;
  if (e >= EP) return;
  int d, s;
  if (e < E) { d = dst[e]; s = src[e]; } else { d = e - E; s = e - E; }
  int pos = atomicAdd(&fillc[d], 1);
  srcl[indptr[d] + pos] = s;
}

// ============ GAT: per-node attention logits (bf16 xh) ============
__global__ void gat_att_kernel(const unsigned short* __restrict__ xhb,
                               const float* __restrict__ attS, const float* __restrict__ attD,
                               float* __restrict__ aS, float* __restrict__ aD, int n)
{
  int idx = blockIdx.x * blockDim.x + threadIdx.x;
  if (idx >= n * 4) return;
  int nn = idx >> 2, hd = idx & 3;
  const uint4* xr = (const uint4*)(xhb + (size_t)nn * 128 + hd * 32);
  const float* as_ = attS + hd * 32;
  const float* ad_ = attD + hd * 32;
  float s = 0.f, d = 0.f;
#pragma unroll
  for (int w = 0; w < 4; ++w) {
    uint4 v = xr[w];
    unsigned int u[4] = {v.x, v.y, v.z, v.w};
#pragma unroll
    for (int c = 0; c < 4; ++c) {
      float lo = b2f((unsigned short)(u[c] & 0xffff));
      float hi = b2f((unsigned short)(u[c] >> 16));
      int o = w * 8 + c * 2;
      s = fmaf(lo, as_[o], s);     d = fmaf(lo, ad_[o], d);
      s = fmaf(hi, as_[o + 1], s); d = fmaf(hi, ad_[o + 1], d);
    }
  }
  aS[idx] = s; aD[idx] = d;
}

// ============ GAT: fused softmax + weighted gather (wave per dst), x2 unrolled ============
__global__ __launch_bounds__(256)
void gat_fused_kernel(const unsigned short* __restrict__ xhb,
                      const float* __restrict__ aS, const float* __restrict__ aD,
                      const int* __restrict__ indptr, const int* __restrict__ srcl,
                      const float* __restrict__ bgat, unsigned short* __restrict__ outb,
                      int ldo, int n)
{
  int wid = (int)((blockIdx.x * (size_t)blockDim.x + threadIdx.x) >> 6);
  int lane = threadIdx.x & 63;
  if (wid >= n) return;
  int eb = indptr[wid], ee = indptr[wid + 1];
  float4 ad = ld4(aD + wid * 4);
  float m0 = -3e38f, m1 = -3e38f, m2 = -3e38f, m3 = -3e38f;
  for (int i = eb + lane; i < ee; i += 64) {
    int s = srcl[i];
    float4 as = ld4(aS + s * 4);
    float e0 = as.x + ad.x; e0 = e0 > 0.f ? e0 : 0.2f * e0; m0 = fmaxf(m0, e0);
    float e1 = as.y + ad.y; e1 = e1 > 0.f ? e1 : 0.2f * e1; m1 = fmaxf(m1, e1);
    float e2 = as.z + ad.z; e2 = e2 > 0.f ? e2 : 0.2f * e2; m2 = fmaxf(m2, e2);
    float e3 = as.w + ad.w; e3 = e3 > 0.f ? e3 : 0.2f * e3; m3 = fmaxf(m3, e3);
  }
#pragma unroll
  for (int off = 32; off; off >>= 1) {
    m0 = fmaxf(m0, __shfl_xor(m0, off)); m1 = fmaxf(m1, __shfl_xor(m1, off));
    m2 = fmaxf(m2, __shfl_xor(m2, off)); m3 = fmaxf(m3, __shfl_xor(m3, off));
  }
  int hsel = lane >> 4;
  float mh  = (hsel == 0) ? m0 : (hsel == 1) ? m1 : (hsel == 2) ? m2 : m3;
  float adh = (hsel == 0) ? ad.x : (hsel == 1) ? ad.y : (hsel == 2) ? ad.z : ad.w;
  float sum = 0.f, acc0 = 0.f, acc1 = 0.f;
  int i = eb;
  for (; i + 1 < ee; i += 2) {
    int s0 = srcl[i], s1 = srcl[i + 1];
    float e0 = aS[s0 * 4 + hsel] + adh; e0 = e0 > 0.f ? e0 : 0.2f * e0;
    float e1 = aS[s1 * 4 + hsel] + adh; e1 = e1 > 0.f ? e1 : 0.2f * e1;
    unsigned int px0 = *(const unsigned int*)(xhb + (size_t)s0 * 128 + lane * 2);
    unsigned int px1 = *(const unsigned int*)(xhb + (size_t)s1 * 128 + lane * 2);
    float p0 = __expf(e0 - mh);
    float p1 = __expf(e1 - mh);
    sum += p0 + p1;
    acc0 = fmaf(p0, b2f((unsigned short)(px0 & 0xffff)), acc0);
    acc1 = fmaf(p0, b2f((unsigned short)(px0 >> 16)), acc1);
    acc0 = fmaf(p1, b2f((unsigned short)(px1 & 0xffff)), acc0);
    acc1 = fmaf(p1, b2f((unsigned short)(px1 >> 16)), acc1);
  }
  if (i < ee) {
    int s = srcl[i];
    float e = aS[s * 4 + hsel] + adh; e = e > 0.f ? e : 0.2f * e;
    float p = __expf(e - mh);
    sum += p;
    unsigned int px = *(const unsigned int*)(xhb + (size_t)s * 128 + lane * 2);
    acc0 = fmaf(p, b2f((unsigned short)(px & 0xffff)), acc0);
    acc1 = fmaf(p, b2f((unsigned short)(px >> 16)), acc1);
  }
  float dv = 1.f / (sum + 1e-16f);
  float ox = acc0 * dv + bgat[lane * 2];
  float oy = acc1 * dv + bgat[lane * 2 + 1];
  unsigned int pk = (unsigned int)f2b(ox) | ((unsigned int)f2b(oy) << 16);
  *reinterpret_cast<unsigned int*>(outb + (size_t)wid * ldo + lane * 2) = pk;
}

// ============ impact head layer 2 + |.| mean ============
__global__ __launch_bounds__(256)
void impact_out_kernel(const float* __restrict__ hid, const float* __restrict__ W2,
                       const float* __restrict__ b2, float* __restrict__ outp,
                       float* __restrict__ total, float wk, int n)
{
  __shared__ float red[256];
  int idx = blockIdx.x * 256 + threadIdx.x;
  float part = 0.f;
  if (idx < n) {
    const float* h = hid + (size_t)idx * 64;
    float o0 = b2[0], o1 = b2[1], o2 = b2[2];
#pragma unroll 8
    for (int k = 0; k < 64; ++k) {
      float v = h[k];
      o0 = fmaf(v, W2[k * 3 + 0], o0);
      o1 = fmaf(v, W2[k * 3 + 1], o1);
      o2 = fmaf(v, W2[k * 3 + 2], o2);
    }
    outp[(size_t)idx * 3 + 0] = o0;
    outp[(size_t)idx * 3 + 1] = o1;
    outp[(size_t)idx * 3 + 2] = o2;
    part = fabsf(o0) + fabsf(o1) + fabsf(o2);
  }
  red[threadIdx.x] = part;
  __syncthreads();
  for (int s = 128; s; s >>= 1) {
    if (threadIdx.x < s) red[threadIdx.x] += red[threadIdx.x + s];
    __syncthreads();
  }
  if (threadIdx.x == 0) atomicAdd(total, red[0] * wk);
}

// ============ host ============
extern "C" void kernel_launch(void* const* d_in, const int* in_sizes, int n_in,
                              void* d_out, int out_size, void* d_ws, size_t ws_size,
                              hipStream_t stream)
{
  const float* x     = (const float*)d_in[0];
  const int*   ei    = (const int*)  d_in[1];
  const float* mask  = (const float*)d_in[2];
  const float* itype = (const float*)d_in[3];
  const float* Wenc  = (const float*)d_in[4];
  const float* benc  = (const float*)d_in[5];
  const float* Wgat  = (const float*)d_in[6];
  const float* attS  = (const float*)d_in[7];
  const float* attD  = (const float*)d_in[8];
  const float* bgat  = (const float*)d_in[9];
  const float* W1    = (const float*)d_in[10];
  const float* b1    = (const float*)d_in[11];
  const float* W2    = (const float*)d_in[12];
  const float* b2    = (const float*)d_in[13];
  const float* Wih0  = (const float*)d_in[14];
  const float* Whh0  = (const float*)d_in[15];
  const float* bih0  = (const float*)d_in[16];
  const float* bhh0  = (const float*)d_in[17];
  const float* Wih1  = (const float*)d_in[18];
  const float* Whh1  = (const float*)d_in[19];
  const float* bih1  = (const float*)d_in[20];
  const float* bhh1  = (const float*)d_in[21];

  const int N  = in_sizes[0] / 128;
  const int E  = in_sizes[1] / 2;
  const int EP = E + N;

  float* out      = (float*)d_out;
  float* impacts  = out;
  float* temporal = out + (size_t)3 * N * 3;
  float* hlast    = temporal + (size_t)N * 384;
  float* total    = hlast + (size_t)N * 128;

  // ---- workspace layout ----
  float* ws = (float*)d_ws;
  float* c0 = ws;
  float* c1 = c0 + (size_t)N * 128;
  unsigned short* tempb = (unsigned short*)(c1 + (size_t)N * 128);
  unsigned short* hb0   = tempb + (size_t)N * 384;
  unsigned short* xhb   = hb0 + (size_t)N * 128;
  int* indptr = (int*)(xhb + (size_t)N * 128);
  int* fillc  = indptr + (N + 1);
  int* srcl   = fillc + N;
  int* bsum   = srcl + EP;
  size_t ip = (size_t)((bsum + 256) - (int*)ws);
  ip = (ip + 7) & ~(size_t)7;
  unsigned short* frags = (unsigned short*)((int*)ws + ip);
  unsigned short* WencF = frags;
  unsigned short* WgatF = WencF + 16384;
  unsigned short* W1F   = WgatF + 3 * 16384;
  unsigned short* L0F   = W1F + 3 * 8192;
  unsigned short* L1F   = L0F + 131072;

  float* regA = c1;
  float* aS   = c0;
  float* aD   = c0 + (size_t)N * 4;

  size_t need = ((size_t)N * 128 * 2) * 4 + (size_t)N * 384 * 2 + (size_t)N * 128 * 2 * 2
              + ((size_t)2 * N + 1 + EP + 264) * 4 + (size_t)(16384 * 4 + 8192 * 3 + 131072 * 2) * 2 + 64;
  if (ws_size < need) return;

  const int* esrc = ei;
  const int* edst = ei + E;
  const int rowTiles = (N + 63) / 64;
  const int nscan = (N + 1023) / 1024;

  // ---- build weight fragments ----
  build_frag_kmajor<<<64, 256, 0, stream>>>(Wenc, 128, WencF, 4, 8);
  for (int k = 0; k < 3; ++k) {
    build_frag_kmajor<<<64, 256, 0, stream>>>(Wgat + (size_t)k * 16384, 128, WgatF + (size_t)k * 16384, 4, 8);
    build_frag_kmajor<<<32, 256, 0, stream>>>(W1 + (size_t)k * 8192, 64, W1F + (size_t)k * 8192, 4, 4);
  }
  build_frag_lstm3<<<512, 256, 0, stream>>>(Wih0, Whh0, L0F);
  build_frag_lstm3<<<512, 256, 0, stream>>>(Wih1, Whh1, L1F);

  // ---- CSR by destination, two-level scan ----
  hipMemsetAsync(fillc, 0, (size_t)N * sizeof(int), stream);
  count_kernel<<<(EP + 255) / 256, 256, 0, stream>>>(edst, fillc, E, EP);
  scan1_kernel<<<nscan, 1024, 0, stream>>>(fillc, indptr, bsum, N);
  scan2_kernel<<<1, 64, 0, stream>>>(bsum, indptr, nscan, N);
  scan3_kernel<<<nscan, 1024, 0, stream>>>(indptr, bsum, N);
  hipMemsetAsync(fillc, 0, (size_t)N * sizeof(int), stream);
  fill_kernel<<<(EP + 255) / 256, 256, 0, stream>>>(esrc, edst, indptr, fillc, srcl, E, EP);

  // ---- encoder ----
  gemm_mfma<8, 4, 0, 0, 0><<<dim3(rowTiles, 1), 256, 0, stream>>>(
      x, 128, WencF, 8, c0, nullptr, 128, nullptr, N);
  encoder_finish_kernel<<<(N * 128 + 255) / 256, 256, 0, stream>>>(c0, itype, mask, Wenc, benc, hb0, N);

  hipMemsetAsync(total, 0, sizeof(float), stream);

  const int waveGrid = (N * 64 + 255) / 256;

  // ---- 3 GAT hops + impact heads ----
  for (int k = 0; k < 3; ++k) {
    const unsigned short* hinb = (k == 0) ? hb0 : (tempb + (size_t)(k - 1) * 128);
    int ldin = (k == 0) ? 128 : 384;
    gemm_mfma<8, 4, 1, 0, 1><<<dim3(rowTiles, 1), 256, 0, stream>>>(
        hinb, ldin, WgatF + (size_t)k * 16384, 8, nullptr, xhb, 128, nullptr, N);
    gat_att_kernel<<<(N * 4 + 255) / 256, 256, 0, stream>>>(xhb, attS + k * 128, attD + k * 128, aS, aD, N);
    gat_fused_kernel<<<waveGrid, 256, 0, stream>>>(xhb, aS, aD, indptr, srcl, bgat + k * 128,
                                                   tempb + (size_t)k * 128, 384, N);
    gemm_mfma<4, 4, 0, 1, 1><<<dim3(rowTiles, 1), 256, 0, stream>>>(
        tempb + (size_t)k * 128, 384, W1F + (size_t)k * 8192, 4,
        regA, nullptr, 64, b1 + k * 64, N);
    float wk = ((k == 0) ? 1.f : (k == 1) ? 0.5f : 0.25f) / (3.0f * (float)N);
    impact_out_kernel<<<(N + 255) / 256, 256, 0, stream>>>(regA, W2 + k * 192, b2 + k * 3,
                                                           impacts + (size_t)k * N * 3, total, wk, N);
  }

  // ---- fully fused LSTM: 3 row-tiles per block (weight reuse) ----
  const int lgrid = (rowTiles + 2) / 3;
  lstm_fused<<<lgrid, 512, 0, stream>>>(tempb, L0F, L1F, bih0, bhh0, bih1, bhh1,
                                        temporal, hlast, N);
}

// Round 15
// 1691.573 us; speedup vs baseline: 1.0767x; 1.0767x over previous
//
#include <hip/hip_runtime.h>

typedef __attribute__((ext_vector_type(8))) short short8;
typedef __attribute__((ext_vector_type(4))) float f32x4;

__device__ __forceinline__ float4 ld4(const float* p){ return *reinterpret_cast<const float4*>(p); }
__device__ __forceinline__ void st4(float* p, const float4& v){ *reinterpret_cast<float4*>(p) = v; }

__device__ __forceinline__ unsigned short f2b(float x){
  unsigned int u = __float_as_uint(x);
  unsigned int r = (u + 0x7fffu + ((u >> 16) & 1u)) >> 16;
  return (unsigned short)r;
}
__device__ __forceinline__ float b2f(unsigned short b){
  return __uint_as_float(((unsigned int)b) << 16);
}

__device__ __forceinline__ float fsigmoid(float x){ return 1.f / (1.f + __expf(-x)); }
__device__ __forceinline__ float ftanh(float x){ return 1.f - 2.f / (1.f + __expf(2.f * x)); }

__device__ __forceinline__ short8 cvt_frag(float4 f0, float4 f1){
  short8 a;
  a[0]=(short)f2b(f0.x); a[1]=(short)f2b(f0.y); a[2]=(short)f2b(f0.z); a[3]=(short)f2b(f0.w);
  a[4]=(short)f2b(f1.x); a[5]=(short)f2b(f1.y); a[6]=(short)f2b(f1.z); a[7]=(short)f2b(f1.w);
  return a;
}

// ============ weight fragmentization ============
__global__ void build_frag_kmajor(const float* __restrict__ B, int ldb,
                                  unsigned short* __restrict__ BF, int KB, int CTG)
{
  int idx = blockIdx.x * 256 + threadIdx.x;
  int total = KB * CTG * 512;
  if (idx >= total) return;
  int j = idx & 7, lane = (idx >> 3) & 63, rest = idx >> 9;
  int ctg = rest % CTG, kb = rest / CTG;
  int k = kb * 32 + ((lane >> 4) << 3) + j;
  int col = ctg * 16 + (lane & 15);
  BF[idx] = f2b(B[(size_t)k * ldb + col]);
}

// LSTM wave-slice layout (8 waves x 16 j-cols each), round-5 layout
__global__ void build_frag_lstm3(const float* __restrict__ Wih, const float* __restrict__ Whh,
                                 unsigned short* __restrict__ BF)
{
  int idx = blockIdx.x * 256 + threadIdx.x;
  if (idx >= 131072) return;
  int j = idx & 7, lane = (idx >> 3) & 63;
  int g = (idx >> 9) & 3, kb = (idx >> 11) & 7, w = idx >> 14;
  int col = g * 128 + w * 16 + (lane & 15);
  int k = kb * 32 + ((lane >> 4) << 3) + j;
  float v = (k < 128) ? Wih[(size_t)col * 128 + k] : Whh[(size_t)col * 128 + (k - 128)];
  BF[idx] = f2b(v);
}

// ============ generic MFMA GEMM (+optional fused attention logits) ============
template<int CT, int KB, int OUTBF, int RELU, int ABF16, int ATT>
__global__ __launch_bounds__(256)
void gemm_mfma(const void* __restrict__ Av, int lda,
               const unsigned short* __restrict__ BF, int ctgTot,
               float* __restrict__ Cf, unsigned short* __restrict__ Cb, int ldc,
               const float* __restrict__ bias, int nrows,
               const float* __restrict__ attS, const float* __restrict__ attD,
               float* __restrict__ aSo, float* __restrict__ aDo)
{
  const int tid = threadIdx.x, lane = tid & 63, wid = tid >> 6;
  const int row0 = blockIdx.x * 64 + wid * 16;
  const int cg = blockIdx.y * CT;
  const int r = row0 + (lane & 15);
  const bool rok = r < nrows;
  const int koff = (lane >> 4) << 3;
  const int c15 = lane & 15;

  f32x4 acc[CT];
#pragma unroll
  for (int ct = 0; ct < CT; ++ct) {
    float b = bias ? bias[(cg + ct) * 16 + c15] : 0.f;
    acc[ct] = (f32x4){b, b, b, b};
  }

#pragma unroll
  for (int kb = 0; kb < KB; ++kb) {
    short8 a = {};
    if (rok) {
      if (ABF16) {
        a = *(const short8*)((const unsigned short*)Av + (size_t)r * lda + kb * 32 + koff);
      } else {
        const float* p = (const float*)Av + (size_t)r * lda + kb * 32 + koff;
        a = cvt_frag(ld4(p), ld4(p + 4));
      }
    }
#pragma unroll
    for (int ct = 0; ct < CT; ++ct) {
      const short8 b = *(const short8*)(BF + ((size_t)(kb * ctgTot + cg + ct) * 64 + lane) * 8);
      acc[ct] = __builtin_amdgcn_mfma_f32_16x16x32_bf16(a, b, acc[ct], 0, 0, 0);
    }
  }

  const int orow = row0 + ((lane >> 4) << 2);
#pragma unroll
  for (int ct = 0; ct < CT; ++ct) {
    int col = (cg + ct) * 16 + c15;
#pragma unroll
    for (int rg = 0; rg < 4; ++rg) {
      int rr = orow + rg;
      if (rr >= nrows) continue;
      float v = acc[ct][rg];
      if (RELU) v = fmaxf(v, 0.f);
      if (OUTBF) Cb[(size_t)rr * ldc + col] = f2b(v);
      else       Cf[(size_t)rr * ldc + col] = v;
    }
  }

  if (ATT) {
    // fused attention logits: aS[r][h] = sum_o xh[r][h*32+o]*attS[h*32+o] (same for aD)
    float s0c[4], s1c[4], d0c[4], d1c[4];
#pragma unroll
    for (int h = 0; h < 4; ++h) {
      s0c[h] = attS[h * 32 + c15];
      s1c[h] = attS[h * 32 + 16 + c15];
      d0c[h] = attD[h * 32 + c15];
      d1c[h] = attD[h * 32 + 16 + c15];
    }
    f32x4 pS[4], pD[4];
#pragma unroll
    for (int h = 0; h < 4; ++h) {
#pragma unroll
      for (int rg = 0; rg < 4; ++rg) {
        pS[h][rg] = acc[2 * h][rg] * s0c[h] + acc[2 * h + 1][rg] * s1c[h];
        pD[h][rg] = acc[2 * h][rg] * d0c[h] + acc[2 * h + 1][rg] * d1c[h];
      }
    }
#pragma unroll
    for (int off = 1; off < 16; off <<= 1) {
#pragma unroll
      for (int h = 0; h < 4; ++h) {
#pragma unroll
        for (int rg = 0; rg < 4; ++rg) {
          pS[h][rg] += __shfl_xor(pS[h][rg], off);
          pD[h][rg] += __shfl_xor(pD[h][rg], off);
        }
      }
    }
    if (c15 == 0) {
#pragma unroll
      for (int rg = 0; rg < 4; ++rg) {
        int rr = orow + rg;
        if (rr < nrows) {
          st4(aSo + (size_t)rr * 4, make_float4(pS[0][rg], pS[1][rg], pS[2][rg], pS[3][rg]));
          st4(aDo + (size_t)rr * 4, make_float4(pD[0][rg], pD[1][rg], pD[2][rg], pD[3][rg]));
        }
      }
    }
  }
}

// ============ fully fused 2-layer x T=3 LSTM (r13 best: 64-row blocks, coalesced epilogue) ============
__global__ __launch_bounds__(512, 2)
void lstm_fused(const unsigned short* __restrict__ tempb,
                const unsigned short* __restrict__ L0F, const unsigned short* __restrict__ L1F,
                const float* __restrict__ bih0, const float* __restrict__ bhh0,
                const float* __restrict__ bih1, const float* __restrict__ bhh1,
                float* __restrict__ temporal, float* __restrict__ hlast, int nrows)
{
  __shared__ unsigned short h0b[8192];
  __shared__ unsigned short h1b[8192];
  __shared__ float h1f[64 * 132];
  const int tid = threadIdx.x, lane = tid & 63, w = tid >> 6;
  const int row0 = blockIdx.x * 64;
  const int rbase = lane & 15;
  const int koff = (lane >> 4) << 3;
  const int c15 = lane & 15;
  const int jw = w * 16;

  float bs0[4], bs1[4];
#pragma unroll
  for (int g = 0; g < 4; ++g) {
    int col = g * 128 + jw + c15;
    bs0[g] = bih0[col] + bhh0[col];
    bs1[g] = bih1[col] + bhh1[col];
  }

  f32x4 c0[4], c1[4];
#pragma unroll
  for (int i = 0; i < 4; ++i) { c0[i] = (f32x4){0,0,0,0}; c1[i] = (f32x4){0,0,0,0}; }

  const unsigned short* BF0 = L0F + (size_t)w * 16384;
  const unsigned short* BF1 = L1F + (size_t)w * 16384;

  f32x4 acc[4][4];

  for (int t = 0; t < 3; ++t) {
    // ---------- layer 0 ----------
#pragma unroll
    for (int rf = 0; rf < 4; ++rf)
#pragma unroll
      for (int g = 0; g < 4; ++g) acc[rf][g] = (f32x4){bs0[g], bs0[g], bs0[g], bs0[g]};

#pragma unroll
    for (int kb = 0; kb < 4; ++kb) {
      short8 a[4];
#pragma unroll
      for (int rf = 0; rf < 4; ++rf) {
        int r = row0 + rf * 16 + rbase;
        a[rf] = (r < nrows) ? *(const short8*)(tempb + (size_t)r * 384 + t * 128 + kb * 32 + koff)
                            : (short8){0,0,0,0,0,0,0,0};
      }
#pragma unroll
      for (int g = 0; g < 4; ++g) {
        const short8 b = *(const short8*)(BF0 + (((size_t)kb * 4 + g) * 64 + lane) * 8);
#pragma unroll
        for (int rf = 0; rf < 4; ++rf)
          acc[rf][g] = __builtin_amdgcn_mfma_f32_16x16x32_bf16(a[rf], b, acc[rf][g], 0, 0, 0);
      }
    }
    if (t > 0) {
#pragma unroll
      for (int kb = 4; kb < 8; ++kb) {
        short8 a[4];
#pragma unroll
        for (int rf = 0; rf < 4; ++rf) {
          int rl = rf * 16 + rbase;
          int kk = (kb - 4) * 32 + koff;
          a[rf] = *(const short8*)(h0b + rl * 128 + (kk ^ ((rl & 7) << 3)));
        }
#pragma unroll
        for (int g = 0; g < 4; ++g) {
          const short8 b = *(const short8*)(BF0 + (((size_t)kb * 4 + g) * 64 + lane) * 8);
#pragma unroll
          for (int rf = 0; rf < 4; ++rf)
            acc[rf][g] = __builtin_amdgcn_mfma_f32_16x16x32_bf16(a[rf], b, acc[rf][g], 0, 0, 0);
        }
      }
    }

    __syncthreads();  // A

#pragma unroll
    for (int rf = 0; rf < 4; ++rf) {
      int j = jw + c15;
#pragma unroll
      for (int rg = 0; rg < 4; ++rg) {
        float si = fsigmoid(acc[rf][0][rg]);
        float sf = fsigmoid(acc[rf][1][rg]);
        float gg = ftanh(acc[rf][2][rg]);
        float so = fsigmoid(acc[rf][3][rg]);
        float c = sf * c0[rf][rg] + si * gg;
        c0[rf][rg] = c;
        float hh = so * ftanh(c);
        int rl = rf * 16 + ((lane >> 4) << 2) + rg;
        h0b[rl * 128 + (j ^ ((rl & 7) << 3))] = f2b(hh);
      }
    }

    __syncthreads();  // B

    // ---------- layer 1 ----------
#pragma unroll
    for (int rf = 0; rf < 4; ++rf)
#pragma unroll
      for (int g = 0; g < 4; ++g) acc[rf][g] = (f32x4){bs1[g], bs1[g], bs1[g], bs1[g]};

#pragma unroll
    for (int kb = 0; kb < 4; ++kb) {
      short8 a[4];
#pragma unroll
      for (int rf = 0; rf < 4; ++rf) {
        int rl = rf * 16 + rbase;
        int kk = kb * 32 + koff;
        a[rf] = *(const short8*)(h0b + rl * 128 + (kk ^ ((rl & 7) << 3)));
      }
#pragma unroll
      for (int g = 0; g < 4; ++g) {
        const short8 b = *(const short8*)(BF1 + (((size_t)kb * 4 + g) * 64 + lane) * 8);
#pragma unroll
        for (int rf = 0; rf < 4; ++rf)
          acc[rf][g] = __builtin_amdgcn_mfma_f32_16x16x32_bf16(a[rf], b, acc[rf][g], 0, 0, 0);
      }
    }
    if (t > 0) {
#pragma unroll
      for (int kb = 4; kb < 8; ++kb) {
        short8 a[4];
#pragma unroll
        for (int rf = 0; rf < 4; ++rf) {
          int rl = rf * 16 + rbase;
          int kk = (kb - 4) * 32 + koff;
          a[rf] = *(const short8*)(h1b + rl * 128 + (kk ^ ((rl & 7) << 3)));
        }
#pragma unroll
        for (int g = 0; g < 4; ++g) {
          const short8 b = *(const short8*)(BF1 + (((size_t)kb * 4 + g) * 64 + lane) * 8);
#pragma unroll
          for (int rf = 0; rf < 4; ++rf)
            acc[rf][g] = __builtin_amdgcn_mfma_f32_16x16x32_bf16(a[rf], b, acc[rf][g], 0, 0, 0);
        }
      }
    }

    __syncthreads();  // C

#pragma unroll
    for (int rf = 0; rf < 4; ++rf) {
      int j = jw + c15;
#pragma unroll
      for (int rg = 0; rg < 4; ++rg) {
        float si = fsigmoid(acc[rf][0][rg]);
        float sf = fsigmoid(acc[rf][1][rg]);
        float gg = ftanh(acc[rf][2][rg]);
        float so = fsigmoid(acc[rf][3][rg]);
        float c = sf * c1[rf][rg] + si * gg;
        c1[rf][rg] = c;
        float hh = so * ftanh(c);
        int rl = rf * 16 + ((lane >> 4) << 2) + rg;
        h1b[rl * 128 + (j ^ ((rl & 7) << 3))] = f2b(hh);
        h1f[rl * 132 + j] = hh;
      }
    }

    __syncthreads();  // D

#pragma unroll
    for (int k = 0; k < 4; ++k) {
      int idx = tid + k * 512;
      int row = idx >> 5;
      int c4 = (idx & 31) << 2;
      int r = row0 + row;
      if (r < nrows) {
        float4 v = ld4(&h1f[row * 132 + c4]);
        st4(&temporal[(size_t)r * 384 + t * 128 + c4], v);
        if (t == 2) st4(&hlast[(size_t)r * 128 + c4], v);
      }
    }
  }
}

// ============ encoder tail ============
__global__ void encoder_finish_kernel(const float* __restrict__ pre, const float* __restrict__ itype,
                                      const float* __restrict__ mask, const float* __restrict__ Wenc,
                                      const float* __restrict__ benc, unsigned short* __restrict__ hb, int n)
{
  int idx = blockIdx.x * blockDim.x + threadIdx.x;
  if (idx >= n * 128) return;
  int nn = idx >> 7, j = idx & 127;
  float v = pre[idx]
          + itype[nn * 3 + 0] * Wenc[128 * 128 + j]
          + itype[nn * 3 + 1] * Wenc[129 * 128 + j]
          + itype[nn * 3 + 2] * Wenc[130 * 128 + j]
          + benc[j];
  hb[idx] = f2b(fmaxf(v, 0.f) * mask[nn]);
}

// ============ CSR build ============
__global__ void count_kernel(const int* __restrict__ dst, int* __restrict__ cnt, int E, int EP)
{
  int e = blockIdx.x * blockDim.x + threadIdx.x;
  if (e >= EP) return;
  int d = (e < E) ? dst[e] : (e - E);
  atomicAdd(&cnt[d], 1);
}

__global__ __launch_bounds__(1024)
void scan1_kernel(const int* __restrict__ cnt, int* __restrict__ indptr,
                  int* __restrict__ bsum, int n)
{
  __shared__ int wsum[16];
  int tid = threadIdx.x;
  int lane = tid & 63, wv = tid >> 6;
  int idx = blockIdx.x * 1024 + tid;
  int v = (idx < n) ? cnt[idx] : 0;
  int x = v;
#pragma unroll
  for (int off = 1; off < 64; off <<= 1) { int y = __shfl_up(x, off); if (lane >= off) x += y; }
  if (lane == 63) wsum[wv] = x;
  __syncthreads();
  if (wv == 0) {
    int t = (lane < 16) ? wsum[lane] : 0;
#pragma unroll
    for (int off = 1; off < 16; off <<= 1) { int y = __shfl_up(t, off); if (lane >= off) t += y; }
    if (lane < 16) wsum[lane] = t;
  }
  __syncthreads();
  int offs = wv ? wsum[wv - 1] : 0;
  if (idx < n) indptr[idx] = offs + x - v;
  if (tid == 0) bsum[blockIdx.x] = wsum[15];
}

__global__ void scan2_kernel(int* __restrict__ bsum, int* __restrict__ indptr, int nb, int n)
{
  if (threadIdx.x == 0 && blockIdx.x == 0) {
    int run = 0;
    for (int i = 0; i < nb; ++i) { int t = bsum[i]; bsum[i] = run; run += t; }
    indptr[n] = run;
  }
}

__global__ __launch_bounds__(1024)
void scan3_kernel(int* __restrict__ indptr, const int* __restrict__ bsum, int n)
{
  int idx = blockIdx.x * 1024 + threadIdx.x;
  if (idx < n) indptr[idx] += bsum[blockIdx.x];
}

__global__ void fill_kernel(const int* __restrict__ src, const int* __restrict__ dst,
                            const int* __restrict__ indptr, int* __restrict__ fillc,
                            int* __restrict__ srcl, int E, int EP)
{
  int e = blockIdx.x * blockDim.x + threadIdx.x;
  if (e >= EP) return;
  int d, s;
  if (e < E) { d = dst[e]; s = src[e]; } else { d = e - E; s = e - E; }
  int pos = atomicAdd(&fillc[d], 1);
  srcl[indptr[d] + pos] = s;
}

// ============ GAT: fused softmax + weighted gather (wave per dst), x2 unrolled ============
__global__ __launch_bounds__(256)
void gat_fused_kernel(const unsigned short* __restrict__ xhb,
                      const float* __restrict__ aS, const float* __restrict__ aD,
                      const int* __restrict__ indptr, const int* __restrict__ srcl,
                      const float* __restrict__ bgat, unsigned short* __restrict__ outb,
                      int ldo, int n)
{
  int wid = (int)((blockIdx.x * (size_t)blockDim.x + threadIdx.x) >> 6);
  int lane = threadIdx.x & 63;
  if (wid >= n) return;
  int eb = indptr[wid], ee = indptr[wid + 1];
  float4 ad = ld4(aD + wid * 4);
  float m0 = -3e38f, m1 = -3e38f, m2 = -3e38f, m3 = -3e38f;
  for (int i = eb + lane; i < ee; i += 64) {
    int s = srcl[i];
    float4 as = ld4(aS + s * 4);
    float e0 = as.x + ad.x; e0 = e0 > 0.f ? e0 : 0.2f * e0; m0 = fmaxf(m0, e0);
    float e1 = as.y + ad.y; e1 = e1 > 0.f ? e1 : 0.2f * e1; m1 = fmaxf(m1, e1);
    float e2 = as.z + ad.z; e2 = e2 > 0.f ? e2 : 0.2f * e2; m2 = fmaxf(m2, e2);
    float e3 = as.w + ad.w; e3 = e3 > 0.f ? e3 : 0.2f * e3; m3 = fmaxf(m3, e3);
  }
#pragma unroll
  for (int off = 32; off; off >>= 1) {
    m0 = fmaxf(m0, __shfl_xor(m0, off)); m1 = fmaxf(m1, __shfl_xor(m1, off));
    m2 = fmaxf(m2, __shfl_xor(m2, off)); m3 = fmaxf(m3, __shfl_xor(m3, off));
  }
  int hsel = lane >> 4;
  float mh  = (hsel == 0) ? m0 : (hsel == 1) ? m1 : (hsel == 2) ? m2 : m3;
  float adh = (hsel == 0) ? ad.x : (hsel == 1) ? ad.y : (hsel == 2) ? ad.z : ad.w;
  float sum = 0.f, acc0 = 0.f, acc1 = 0.f;
  int i = eb;
  for (; i + 1 < ee; i += 2) {
    int s0 = srcl[i], s1 = srcl[i + 1];
    float e0 = aS[s0 * 4 + hsel] + adh; e0 = e0 > 0.f ? e0 : 0.2f * e0;
    float e1 = aS[s1 * 4 + hsel] + adh; e1 = e1 > 0.f ? e1 : 0.2f * e1;
    unsigned int px0 = *(const unsigned int*)(xhb + (size_t)s0 * 128 + lane * 2);
    unsigned int px1 = *(const unsigned int*)(xhb + (size_t)s1 * 128 + lane * 2);
    float p0 = __expf(e0 - mh);
    float p1 = __expf(e1 - mh);
    sum += p0 + p1;
    acc0 = fmaf(p0, b2f((unsigned short)(px0 & 0xffff)), acc0);
    acc1 = fmaf(p0, b2f((unsigned short)(px0 >> 16)), acc1);
    acc0 = fmaf(p1, b2f((unsigned short)(px1 & 0xffff)), acc0);
    acc1 = fmaf(p1, b2f((unsigned short)(px1 >> 16)), acc1);
  }
  if (i < ee) {
    int s = srcl[i];
    float e = aS[s * 4 + hsel] + adh; e = e > 0.f ? e : 0.2f * e;
    float p = __expf(e - mh);
    sum += p;
    unsigned int px = *(const unsigned int*)(xhb + (size_t)s * 128 + lane * 2);
    acc0 = fmaf(p, b2f((unsigned short)(px & 0xffff)), acc0);
    acc1 = fmaf(p, b2f((unsigned short)(px >> 16)), acc1);
  }
  float dv = 1.f / (sum + 1e-16f);
  float ox = acc0 * dv + bgat[lane * 2];
  float oy = acc1 * dv + bgat[lane * 2 + 1];
  unsigned int pk = (unsigned int)f2b(ox) | ((unsigned int)f2b(oy) << 16);
  *reinterpret_cast<unsigned int*>(outb + (size_t)wid * ldo + lane * 2) = pk;
}

// ============ impact head layer 2 + |.| mean ============
__global__ __launch_bounds__(256)
void impact_out_kernel(const float* __restrict__ hid, const float* __restrict__ W2,
                       const float* __restrict__ b2, float* __restrict__ outp,
                       float* __restrict__ total, float wk, int n)
{
  __shared__ float red[256];
  int idx = blockIdx.x * 256 + threadIdx.x;
  float part = 0.f;
  if (idx < n) {
    const float* h = hid + (size_t)idx * 64;
    float o0 = b2[0], o1 = b2[1], o2 = b2[2];
#pragma unroll 8
    for (int k = 0; k < 64; ++k) {
      float v = h[k];
      o0 = fmaf(v, W2[k * 3 + 0], o0);
      o1 = fmaf(v, W2[k * 3 + 1], o1);
      o2 = fmaf(v, W2[k * 3 + 2], o2);
    }
    outp[(size_t)idx * 3 + 0] = o0;
    outp[(size_t)idx * 3 + 1] = o1;
    outp[(size_t)idx * 3 + 2] = o2;
    part = fabsf(o0) + fabsf(o1) + fabsf(o2);
  }
  red[threadIdx.x] = part;
  __syncthreads();
  for (int s = 128; s; s >>= 1) {
    if (threadIdx.x < s) red[threadIdx.x] += red[threadIdx.x + s];
    __syncthreads();
  }
  if (threadIdx.x == 0) atomicAdd(total, red[0] * wk);
}

// ============ host ============
extern "C" void kernel_launch(void* const* d_in, const int* in_sizes, int n_in,
                              void* d_out, int out_size, void* d_ws, size_t ws_size,
                              hipStream_t stream)
{
  const float* x     = (const float*)d_in[0];
  const int*   ei    = (const int*)  d_in[1];
  const float* mask  = (const float*)d_in[2];
  const float* itype = (const float*)d_in[3];
  const float* Wenc  = (const float*)d_in[4];
  const float* benc  = (const float*)d_in[5];
  const float* Wgat  = (const float*)d_in[6];
  const float* attS  = (const float*)d_in[7];
  const float* attD  = (const float*)d_in[8];
  const float* bgat  = (const float*)d_in[9];
  const float* W1    = (const float*)d_in[10];
  const float* b1    = (const float*)d_in[11];
  const float* W2    = (const float*)d_in[12];
  const float* b2    = (const float*)d_in[13];
  const float* Wih0  = (const float*)d_in[14];
  const float* Whh0  = (const float*)d_in[15];
  const float* bih0  = (const float*)d_in[16];
  const float* bhh0  = (const float*)d_in[17];
  const float* Wih1  = (const float*)d_in[18];
  const float* Whh1  = (const float*)d_in[19];
  const float* bih1  = (const float*)d_in[20];
  const float* bhh1  = (const float*)d_in[21];

  const int N  = in_sizes[0] / 128;
  const int E  = in_sizes[1] / 2;
  const int EP = E + N;

  float* out      = (float*)d_out;
  float* impacts  = out;
  float* temporal = out + (size_t)3 * N * 3;
  float* hlast    = temporal + (size_t)N * 384;
  float* total    = hlast + (size_t)N * 128;

  // ---- workspace layout ----
  float* ws = (float*)d_ws;
  float* c0 = ws;
  float* c1 = c0 + (size_t)N * 128;
  unsigned short* tempb = (unsigned short*)(c1 + (size_t)N * 128);
  unsigned short* hb0   = tempb + (size_t)N * 384;
  unsigned short* xhb   = hb0 + (size_t)N * 128;
  int* indptr = (int*)(xhb + (size_t)N * 128);
  int* fillc  = indptr + (N + 1);
  int* srcl   = fillc + N;
  int* bsum   = srcl + EP;
  size_t ip = (size_t)((bsum + 256) - (int*)ws);
  ip = (ip + 7) & ~(size_t)7;
  unsigned short* frags = (unsigned short*)((int*)ws + ip);
  unsigned short* WencF = frags;
  unsigned short* WgatF = WencF + 16384;
  unsigned short* W1F   = WgatF + 3 * 16384;
  unsigned short* L0F   = W1F + 3 * 8192;
  unsigned short* L1F   = L0F + 131072;

  float* regA = c1;
  float* aS   = c0;
  float* aD   = c0 + (size_t)N * 4;

  size_t need = ((size_t)N * 128 * 2) * 4 + (size_t)N * 384 * 2 + (size_t)N * 128 * 2 * 2
              + ((size_t)2 * N + 1 + EP + 264) * 4 + (size_t)(16384 * 4 + 8192 * 3 + 131072 * 2) * 2 + 64;
  if (ws_size < need) return;

  const int* esrc = ei;
  const int* edst = ei + E;
  const int rowTiles = (N + 63) / 64;
  const int nscan = (N + 1023) / 1024;

  // ---- build weight fragments ----
  build_frag_kmajor<<<64, 256, 0, stream>>>(Wenc, 128, WencF, 4, 8);
  for (int k = 0; k < 3; ++k) {
    build_frag_kmajor<<<64, 256, 0, stream>>>(Wgat + (size_t)k * 16384, 128, WgatF + (size_t)k * 16384, 4, 8);
    build_frag_kmajor<<<32, 256, 0, stream>>>(W1 + (size_t)k * 8192, 64, W1F + (size_t)k * 8192, 4, 4);
  }
  build_frag_lstm3<<<512, 256, 0, stream>>>(Wih0, Whh0, L0F);
  build_frag_lstm3<<<512, 256, 0, stream>>>(Wih1, Whh1, L1F);

  // ---- CSR by destination, two-level scan ----
  hipMemsetAsync(fillc, 0, (size_t)N * sizeof(int), stream);
  count_kernel<<<(EP + 255) / 256, 256, 0, stream>>>(edst, fillc, E, EP);
  scan1_kernel<<<nscan, 1024, 0, stream>>>(fillc, indptr, bsum, N);
  scan2_kernel<<<1, 64, 0, stream>>>(bsum, indptr, nscan, N);
  scan3_kernel<<<nscan, 1024, 0, stream>>>(indptr, bsum, N);
  hipMemsetAsync(fillc, 0, (size_t)N * sizeof(int), stream);
  fill_kernel<<<(EP + 255) / 256, 256, 0, stream>>>(esrc, edst, indptr, fillc, srcl, E, EP);

  // ---- encoder ----
  gemm_mfma<8, 4, 0, 0, 0, 0><<<dim3(rowTiles, 1), 256, 0, stream>>>(
      x, 128, WencF, 8, c0, nullptr, 128, nullptr, N, nullptr, nullptr, nullptr, nullptr);
  encoder_finish_kernel<<<(N * 128 + 255) / 256, 256, 0, stream>>>(c0, itype, mask, Wenc, benc, hb0, N);

  hipMemsetAsync(total, 0, sizeof(float), stream);

  const int waveGrid = (N * 64 + 255) / 256;

  // ---- 3 GAT hops + impact heads ----
  for (int k = 0; k < 3; ++k) {
    const unsigned short* hinb = (k == 0) ? hb0 : (tempb + (size_t)(k - 1) * 128);
    int ldin = (k == 0) ? 128 : 384;
    // xh GEMM with fused attention logits (replaces gat_att kernel)
    gemm_mfma<8, 4, 1, 0, 1, 1><<<dim3(rowTiles, 1), 256, 0, stream>>>(
        hinb, ldin, WgatF + (size_t)k * 16384, 8, nullptr, xhb, 128, nullptr, N,
        attS + k * 128, attD + k * 128, aS, aD);
    gat_fused_kernel<<<waveGrid, 256, 0, stream>>>(xhb, aS, aD, indptr, srcl, bgat + k * 128,
                                                   tempb + (size_t)k * 128, 384, N);
    gemm_mfma<4, 4, 0, 1, 1, 0><<<dim3(rowTiles, 1), 256, 0, stream>>>(
        tempb + (size_t)k * 128, 384, W1F + (size_t)k * 8192, 4,
        regA, nullptr, 64, b1 + k * 64, N, nullptr, nullptr, nullptr, nullptr);
    float wk = ((k == 0) ? 1.f : (k == 1) ? 0.5f : 0.25f) / (3.0f * (float)N);
    impact_out_kernel<<<(N + 255) / 256, 256, 0, stream>>>(regA, W2 + k * 192, b2 + k * 3,
                                                           impacts + (size_t)k * N * 3, total, wk, N);
  }

  // ---- fully fused LSTM (r13 best: grid = rowTiles) ----
  lstm_fused<<<rowTiles, 512, 0, stream>>>(tempb, L0F, L1F, bih0, bhh0, bih1, bhh1,
                                           temporal, hlast, N);
}

// Round 17
// 1681.333 us; speedup vs baseline: 1.0833x; 1.0061x over previous
//
#include <hip/hip_runtime.h>

typedef __attribute__((ext_vector_type(8))) short short8;
typedef __attribute__((ext_vector_type(4))) float f32x4;

__device__ __forceinline__ float4 ld4(const float* p){ return *reinterpret_cast<const float4*>(p); }
__device__ __forceinline__ void st4(float* p, const float4& v){ *reinterpret_cast<float4*>(p) = v; }

__device__ __forceinline__ unsigned short f2b(float x){
  unsigned int u = __float_as_uint(x);
  unsigned int r = (u + 0x7fffu + ((u >> 16) & 1u)) >> 16;
  return (unsigned short)r;
}
__device__ __forceinline__ float b2f(unsigned short b){
  return __uint_as_float(((unsigned int)b) << 16);
}

__device__ __forceinline__ float fsigmoid(float x){ return 1.f / (1.f + __expf(-x)); }
__device__ __forceinline__ float ftanh(float x){ return 1.f - 2.f / (1.f + __expf(2.f * x)); }

__device__ __forceinline__ short8 cvt_frag(float4 f0, float4 f1){
  short8 a;
  a[0]=(short)f2b(f0.x); a[1]=(short)f2b(f0.y); a[2]=(short)f2b(f0.z); a[3]=(short)f2b(f0.w);
  a[4]=(short)f2b(f1.x); a[5]=(short)f2b(f1.y); a[6]=(short)f2b(f1.z); a[7]=(short)f2b(f1.w);
  return a;
}

// ============ weight fragmentization ============
__global__ void build_frag_kmajor(const float* __restrict__ B, int ldb,
                                  unsigned short* __restrict__ BF, int KB, int CTG)
{
  int idx = blockIdx.x * 256 + threadIdx.x;
  int total = KB * CTG * 512;
  if (idx >= total) return;
  int j = idx & 7, lane = (idx >> 3) & 63, rest = idx >> 9;
  int ctg = rest % CTG, kb = rest / CTG;
  int k = kb * 32 + ((lane >> 4) << 3) + j;
  int col = ctg * 16 + (lane & 15);
  BF[idx] = f2b(B[(size_t)k * ldb + col]);
}

// LSTM wave-slice layout (8 waves x 16 j-cols each), round-5 layout
__global__ void build_frag_lstm3(const float* __restrict__ Wih, const float* __restrict__ Whh,
                                 unsigned short* __restrict__ BF)
{
  int idx = blockIdx.x * 256 + threadIdx.x;
  if (idx >= 131072) return;
  int j = idx & 7, lane = (idx >> 3) & 63;
  int g = (idx >> 9) & 3, kb = (idx >> 11) & 7, w = idx >> 14;
  int col = g * 128 + w * 16 + (lane & 15);
  int k = kb * 32 + ((lane >> 4) << 3) + j;
  float v = (k < 128) ? Wih[(size_t)col * 128 + k] : Whh[(size_t)col * 128 + (k - 128)];
  BF[idx] = f2b(v);
}

// ============ generic MFMA GEMM (+optional fused attention logits) ============
template<int CT, int KB, int OUTBF, int RELU, int ABF16, int ATT>
__global__ __launch_bounds__(256)
void gemm_mfma(const void* __restrict__ Av, int lda,
               const unsigned short* __restrict__ BF, int ctgTot,
               float* __restrict__ Cf, unsigned short* __restrict__ Cb, int ldc,
               const float* __restrict__ bias, int nrows,
               const float* __restrict__ attS, const float* __restrict__ attD,
               float* __restrict__ aSo, float* __restrict__ aDo)
{
  const int tid = threadIdx.x, lane = tid & 63, wid = tid >> 6;
  const int row0 = blockIdx.x * 64 + wid * 16;
  const int cg = blockIdx.y * CT;
  const int r = row0 + (lane & 15);
  const bool rok = r < nrows;
  const int koff = (lane >> 4) << 3;
  const int c15 = lane & 15;

  f32x4 acc[CT];
#pragma unroll
  for (int ct = 0; ct < CT; ++ct) {
    float b = bias ? bias[(cg + ct) * 16 + c15] : 0.f;
    acc[ct] = (f32x4){b, b, b, b};
  }

#pragma unroll
  for (int kb = 0; kb < KB; ++kb) {
    short8 a = {};
    if (rok) {
      if (ABF16) {
        a = *(const short8*)((const unsigned short*)Av + (size_t)r * lda + kb * 32 + koff);
      } else {
        const float* p = (const float*)Av + (size_t)r * lda + kb * 32 + koff;
        a = cvt_frag(ld4(p), ld4(p + 4));
      }
    }
#pragma unroll
    for (int ct = 0; ct < CT; ++ct) {
      const short8 b = *(const short8*)(BF + ((size_t)(kb * ctgTot + cg + ct) * 64 + lane) * 8);
      acc[ct] = __builtin_amdgcn_mfma_f32_16x16x32_bf16(a, b, acc[ct], 0, 0, 0);
    }
  }

  const int orow = row0 + ((lane >> 4) << 2);
#pragma unroll
  for (int ct = 0; ct < CT; ++ct) {
    int col = (cg + ct) * 16 + c15;
#pragma unroll
    for (int rg = 0; rg < 4; ++rg) {
      int rr = orow + rg;
      if (rr >= nrows) continue;
      float v = acc[ct][rg];
      if (RELU) v = fmaxf(v, 0.f);
      if (OUTBF) Cb[(size_t)rr * ldc + col] = f2b(v);
      else       Cf[(size_t)rr * ldc + col] = v;
    }
  }

  if (ATT) {
    float s0c[4], s1c[4], d0c[4], d1c[4];
#pragma unroll
    for (int h = 0; h < 4; ++h) {
      s0c[h] = attS[h * 32 + c15];
      s1c[h] = attS[h * 32 + 16 + c15];
      d0c[h] = attD[h * 32 + c15];
      d1c[h] = attD[h * 32 + 16 + c15];
    }
    f32x4 pS[4], pD[4];
#pragma unroll
    for (int h = 0; h < 4; ++h) {
#pragma unroll
      for (int rg = 0; rg < 4; ++rg) {
        pS[h][rg] = acc[2 * h][rg] * s0c[h] + acc[2 * h + 1][rg] * s1c[h];
        pD[h][rg] = acc[2 * h][rg] * d0c[h] + acc[2 * h + 1][rg] * d1c[h];
      }
    }
#pragma unroll
    for (int off = 1; off < 16; off <<= 1) {
#pragma unroll
      for (int h = 0; h < 4; ++h) {
#pragma unroll
        for (int rg = 0; rg < 4; ++rg) {
          pS[h][rg] += __shfl_xor(pS[h][rg], off);
          pD[h][rg] += __shfl_xor(pD[h][rg], off);
        }
      }
    }
    if (c15 == 0) {
#pragma unroll
      for (int rg = 0; rg < 4; ++rg) {
        int rr = orow + rg;
        if (rr < nrows) {
          st4(aSo + (size_t)rr * 4, make_float4(pS[0][rg], pS[1][rg], pS[2][rg], pS[3][rg]));
          st4(aDo + (size_t)rr * 4, make_float4(pD[0][rg], pD[1][rg], pD[2][rg], pD[3][rg]));
        }
      }
    }
  }
}

// ============ fully fused 2-layer x T=3 LSTM (r13 structure + NT streams) ============
__global__ __launch_bounds__(512, 2)
void lstm_fused(const unsigned short* __restrict__ tempb,
                const unsigned short* __restrict__ L0F, const unsigned short* __restrict__ L1F,
                const float* __restrict__ bih0, const float* __restrict__ bhh0,
                const float* __restrict__ bih1, const float* __restrict__ bhh1,
                float* __restrict__ temporal, float* __restrict__ hlast, int nrows)
{
  __shared__ unsigned short h0b[8192];
  __shared__ unsigned short h1b[8192];
  __shared__ float h1f[64 * 132];
  const int tid = threadIdx.x, lane = tid & 63, w = tid >> 6;
  const int row0 = blockIdx.x * 64;
  const int rbase = lane & 15;
  const int koff = (lane >> 4) << 3;
  const int c15 = lane & 15;
  const int jw = w * 16;

  float bs0[4], bs1[4];
#pragma unroll
  for (int g = 0; g < 4; ++g) {
    int col = g * 128 + jw + c15;
    bs0[g] = bih0[col] + bhh0[col];
    bs1[g] = bih1[col] + bhh1[col];
  }

  f32x4 c0[4], c1[4];
#pragma unroll
  for (int i = 0; i < 4; ++i) { c0[i] = (f32x4){0,0,0,0}; c1[i] = (f32x4){0,0,0,0}; }

  const unsigned short* BF0 = L0F + (size_t)w * 16384;
  const unsigned short* BF1 = L1F + (size_t)w * 16384;

  f32x4 acc[4][4];

  for (int t = 0; t < 3; ++t) {
    // ---------- layer 0 ----------
#pragma unroll
    for (int rf = 0; rf < 4; ++rf)
#pragma unroll
      for (int g = 0; g < 4; ++g) acc[rf][g] = (f32x4){bs0[g], bs0[g], bs0[g], bs0[g]};

#pragma unroll
    for (int kb = 0; kb < 4; ++kb) {
      short8 a[4];
#pragma unroll
      for (int rf = 0; rf < 4; ++rf) {
        int r = row0 + rf * 16 + rbase;
        a[rf] = (r < nrows)
              ? __builtin_nontemporal_load((const short8*)(tempb + (size_t)r * 384 + t * 128 + kb * 32 + koff))
              : (short8){0,0,0,0,0,0,0,0};
      }
#pragma unroll
      for (int g = 0; g < 4; ++g) {
        const short8 b = *(const short8*)(BF0 + (((size_t)kb * 4 + g) * 64 + lane) * 8);
#pragma unroll
        for (int rf = 0; rf < 4; ++rf)
          acc[rf][g] = __builtin_amdgcn_mfma_f32_16x16x32_bf16(a[rf], b, acc[rf][g], 0, 0, 0);
      }
    }
    if (t > 0) {
#pragma unroll
      for (int kb = 4; kb < 8; ++kb) {
        short8 a[4];
#pragma unroll
        for (int rf = 0; rf < 4; ++rf) {
          int rl = rf * 16 + rbase;
          int kk = (kb - 4) * 32 + koff;
          a[rf] = *(const short8*)(h0b + rl * 128 + (kk ^ ((rl & 7) << 3)));
        }
#pragma unroll
        for (int g = 0; g < 4; ++g) {
          const short8 b = *(const short8*)(BF0 + (((size_t)kb * 4 + g) * 64 + lane) * 8);
#pragma unroll
          for (int rf = 0; rf < 4; ++rf)
            acc[rf][g] = __builtin_amdgcn_mfma_f32_16x16x32_bf16(a[rf], b, acc[rf][g], 0, 0, 0);
        }
      }
    }

    __syncthreads();  // A

#pragma unroll
    for (int rf = 0; rf < 4; ++rf) {
      int j = jw + c15;
#pragma unroll
      for (int rg = 0; rg < 4; ++rg) {
        float si = fsigmoid(acc[rf][0][rg]);
        float sf = fsigmoid(acc[rf][1][rg]);
        float gg = ftanh(acc[rf][2][rg]);
        float so = fsigmoid(acc[rf][3][rg]);
        float c = sf * c0[rf][rg] + si * gg;
        c0[rf][rg] = c;
        float hh = so * ftanh(c);
        int rl = rf * 16 + ((lane >> 4) << 2) + rg;
        h0b[rl * 128 + (j ^ ((rl & 7) << 3))] = f2b(hh);
      }
    }

    __syncthreads();  // B

    // ---------- layer 1 ----------
#pragma unroll
    for (int rf = 0; rf < 4; ++rf)
#pragma unroll
      for (int g = 0; g < 4; ++g) acc[rf][g] = (f32x4){bs1[g], bs1[g], bs1[g], bs1[g]};

#pragma unroll
    for (int kb = 0; kb < 4; ++kb) {
      short8 a[4];
#pragma unroll
      for (int rf = 0; rf < 4; ++rf) {
        int rl = rf * 16 + rbase;
        int kk = kb * 32 + koff;
        a[rf] = *(const short8*)(h0b + rl * 128 + (kk ^ ((rl & 7) << 3)));
      }
#pragma unroll
      for (int g = 0; g < 4; ++g) {
        const short8 b = *(const short8*)(BF1 + (((size_t)kb * 4 + g) * 64 + lane) * 8);
#pragma unroll
        for (int rf = 0; rf < 4; ++rf)
          acc[rf][g] = __builtin_amdgcn_mfma_f32_16x16x32_bf16(a[rf], b, acc[rf][g], 0, 0, 0);
      }
    }
    if (t > 0) {
#pragma unroll
      for (int kb = 4; kb < 8; ++kb) {
        short8 a[4];
#pragma unroll
        for (int rf = 0; rf < 4; ++rf) {
          int rl = rf * 16 + rbase;
          int kk = (kb - 4) * 32 + koff;
          a[rf] = *(const short8*)(h1b + rl * 128 + (kk ^ ((rl & 7) << 3)));
        }
#pragma unroll
        for (int g = 0; g < 4; ++g) {
          const short8 b = *(const short8*)(BF1 + (((size_t)kb * 4 + g) * 64 + lane) * 8);
#pragma unroll
          for (int rf = 0; rf < 4; ++rf)
            acc[rf][g] = __builtin_amdgcn_mfma_f32_16x16x32_bf16(a[rf], b, acc[rf][g], 0, 0, 0);
        }
      }
    }

    __syncthreads();  // C

#pragma unroll
    for (int rf = 0; rf < 4; ++rf) {
      int j = jw + c15;
#pragma unroll
      for (int rg = 0; rg < 4; ++rg) {
        float si = fsigmoid(acc[rf][0][rg]);
        float sf = fsigmoid(acc[rf][1][rg]);
        float gg = ftanh(acc[rf][2][rg]);
        float so = fsigmoid(acc[rf][3][rg]);
        float c = sf * c1[rf][rg] + si * gg;
        c1[rf][rg] = c;
        float hh = so * ftanh(c);
        int rl = rf * 16 + ((lane >> 4) << 2) + rg;
        h1b[rl * 128 + (j ^ ((rl & 7) << 3))] = f2b(hh);
        h1f[rl * 132 + j] = hh;
      }
    }

    __syncthreads();  // D

    // coalesced copy-out, nontemporal (native vector type for builtin)
#pragma unroll
    for (int k = 0; k < 4; ++k) {
      int idx = tid + k * 512;
      int row = idx >> 5;
      int c4 = (idx & 31) << 2;
      int r = row0 + row;
      if (r < nrows) {
        f32x4 v = *(const f32x4*)&h1f[row * 132 + c4];
        __builtin_nontemporal_store(v, (f32x4*)&temporal[(size_t)r * 384 + t * 128 + c4]);
        if (t == 2) __builtin_nontemporal_store(v, (f32x4*)&hlast[(size_t)r * 128 + c4]);
      }
    }
  }
}

// ============ encoder tail ============
__global__ void encoder_finish_kernel(const float* __restrict__ pre, const float* __restrict__ itype,
                                      const float* __restrict__ mask, const float* __restrict__ Wenc,
                                      const float* __restrict__ benc, unsigned short* __restrict__ hb, int n)
{
  int idx = blockIdx.x * blockDim.x + threadIdx.x;
  if (idx >= n * 128) return;
  int nn = idx >> 7, j = idx & 127;
  float v = pre[idx]
          + itype[nn * 3 + 0] * Wenc[128 * 128 + j]
          + itype[nn * 3 + 1] * Wenc[129 * 128 + j]
          + itype[nn * 3 + 2] * Wenc[130 * 128 + j]
          + benc[j];
  hb[idx] = f2b(fmaxf(v, 0.f) * mask[nn]);
}

// ============ CSR build ============
__global__ void count_kernel(const int* __restrict__ dst, int* __restrict__ cnt, int E, int EP)
{
  int e = blockIdx.x * blockDim.x + threadIdx.x;
  if (e >= EP) return;
  int d = (e < E) ? dst[e] : (e - E);
  atomicAdd(&cnt[d], 1);
}

__global__ __launch_bounds__(1024)
void scan1_kernel(const int* __restrict__ cnt, int* __restrict__ indptr,
                  int* __restrict__ bsum, int n)
{
  __shared__ int wsum[16];
  int tid = threadIdx.x;
  int lane = tid & 63, wv = tid >> 6;
  int idx = blockIdx.x * 1024 + tid;
  int v = (idx < n) ? cnt[idx] : 0;
  int x = v;
#pragma unroll
  for (int off = 1; off < 64; off <<= 1) { int y = __shfl_up(x, off); if (lane >= off) x += y; }
  if (lane == 63) wsum[wv] = x;
  __syncthreads();
  if (wv == 0) {
    int t = (lane < 16) ? wsum[lane] : 0;
#pragma unroll
    for (int off = 1; off < 16; off <<= 1) { int y = __shfl_up(t, off); if (lane >= off) t += y; }
    if (lane < 16) wsum[lane] = t;
  }
  __syncthreads();
  int offs = wv ? wsum[wv - 1] : 0;
  if (idx < n) indptr[idx] = offs + x - v;
  if (tid == 0) bsum[blockIdx.x] = wsum[15];
}

__global__ void scan2_kernel(int* __restrict__ bsum, int* __restrict__ indptr, int nb, int n)
{
  if (threadIdx.x == 0 && blockIdx.x == 0) {
    int run = 0;
    for (int i = 0; i < nb; ++i) { int t = bsum[i]; bsum[i] = run; run += t; }
    indptr[n] = run;
  }
}

__global__ __launch_bounds__(1024)
void scan3_kernel(int* __restrict__ indptr, const int* __restrict__ bsum, int n)
{
  int idx = blockIdx.x * 1024 + threadIdx.x;
  if (idx < n) indptr[idx] += bsum[blockIdx.x];
}

__global__ void fill_kernel(const int* __restrict__ src, const int* __restrict__ dst,
                            const int* __restrict__ indptr, int* __restrict__ fillc,
                            int* __restrict__ srcl, int E, int EP)
{
  int e = blockIdx.x * blockDim.x + threadIdx.x;
  if (e >= EP) return;
  int d, s;
  if (e < E) { d = dst[e]; s = src[e]; } else { d = e - E; s = e - E; }
  int pos = atomicAdd(&fillc[d], 1);
  srcl[indptr[d] + pos] = s;
}

// ============ GAT: fused softmax + weighted gather — no max pass (shift-invariant) ============
__global__ __launch_bounds__(256)
void gat_fused_kernel(const unsigned short* __restrict__ xhb,
                      const float* __restrict__ aS, const float* __restrict__ aD,
                      const int* __restrict__ indptr, const int* __restrict__ srcl,
                      const float* __restrict__ bgat, unsigned short* __restrict__ outb,
                      int ldo, int n)
{
  int wid = (int)((blockIdx.x * (size_t)blockDim.x + threadIdx.x) >> 6);
  int lane = threadIdx.x & 63;
  if (wid >= n) return;
  int eb = indptr[wid], ee = indptr[wid + 1];
  int hsel = lane >> 4;
  float adh = aD[wid * 4 + hsel];
  float sum = 0.f, acc0 = 0.f, acc1 = 0.f;
  int i = eb;
  for (; i + 1 < ee; i += 2) {
    int s0 = srcl[i], s1 = srcl[i + 1];
    float e0 = aS[s0 * 4 + hsel] + adh; e0 = e0 > 0.f ? e0 : 0.2f * e0;
    float e1 = aS[s1 * 4 + hsel] + adh; e1 = e1 > 0.f ? e1 : 0.2f * e1;
    unsigned int px0 = *(const unsigned int*)(xhb + (size_t)s0 * 128 + lane * 2);
    unsigned int px1 = *(const unsigned int*)(xhb + (size_t)s1 * 128 + lane * 2);
    float p0 = __expf(e0);
    float p1 = __expf(e1);
    sum += p0 + p1;
    acc0 = fmaf(p0, b2f((unsigned short)(px0 & 0xffff)), acc0);
    acc1 = fmaf(p0, b2f((unsigned short)(px0 >> 16)), acc1);
    acc0 = fmaf(p1, b2f((unsigned short)(px1 & 0xffff)), acc0);
    acc1 = fmaf(p1, b2f((unsigned short)(px1 >> 16)), acc1);
  }
  if (i < ee) {
    int s = srcl[i];
    float e = aS[s * 4 + hsel] + adh; e = e > 0.f ? e : 0.2f * e;
    float p = __expf(e);
    sum += p;
    unsigned int px = *(const unsigned int*)(xhb + (size_t)s * 128 + lane * 2);
    acc0 = fmaf(p, b2f((unsigned short)(px & 0xffff)), acc0);
    acc1 = fmaf(p, b2f((unsigned short)(px >> 16)), acc1);
  }
  float dv = 1.f / (sum + 1e-16f);
  float ox = acc0 * dv + bgat[lane * 2];
  float oy = acc1 * dv + bgat[lane * 2 + 1];
  unsigned int pk = (unsigned int)f2b(ox) | ((unsigned int)f2b(oy) << 16);
  *reinterpret_cast<unsigned int*>(outb + (size_t)wid * ldo + lane * 2) = pk;
}

// ============ impact head layer 2 + |.| mean ============
__global__ __launch_bounds__(256)
void impact_out_kernel(const float* __restrict__ hid, const float* __restrict__ W2,
                       const float* __restrict__ b2, float* __restrict__ outp,
                       float* __restrict__ total, float wk, int n)
{
  __shared__ float red[256];
  int idx = blockIdx.x * 256 + threadIdx.x;
  float part = 0.f;
  if (idx < n) {
    const float* h = hid + (size_t)idx * 64;
    float o0 = b2[0], o1 = b2[1], o2 = b2[2];
#pragma unroll 8
    for (int k = 0; k < 64; ++k) {
      float v = h[k];
      o0 = fmaf(v, W2[k * 3 + 0], o0);
      o1 = fmaf(v, W2[k * 3 + 1], o1);
      o2 = fmaf(v, W2[k * 3 + 2], o2);
    }
    outp[(size_t)idx * 3 + 0] = o0;
    outp[(size_t)idx * 3 + 1] = o1;
    outp[(size_t)idx * 3 + 2] = o2;
    part = fabsf(o0) + fabsf(o1) + fabsf(o2);
  }
  red[threadIdx.x] = part;
  __syncthreads();
  for (int s = 128; s; s >>= 1) {
    if (threadIdx.x < s) red[threadIdx.x] += red[threadIdx.x + s];
    __syncthreads();
  }
  if (threadIdx.x == 0) atomicAdd(total, red[0] * wk);
}

// ============ host ============
extern "C" void kernel_launch(void* const* d_in, const int* in_sizes, int n_in,
                              void* d_out, int out_size, void* d_ws, size_t ws_size,
                              hipStream_t stream)
{
  const float* x     = (const float*)d_in[0];
  const int*   ei    = (const int*)  d_in[1];
  const float* mask  = (const float*)d_in[2];
  const float* itype = (const float*)d_in[3];
  const float* Wenc  = (const float*)d_in[4];
  const float* benc  = (const float*)d_in[5];
  const float* Wgat  = (const float*)d_in[6];
  const float* attS  = (const float*)d_in[7];
  const float* attD  = (const float*)d_in[8];
  const float* bgat  = (const float*)d_in[9];
  const float* W1    = (const float*)d_in[10];
  const float* b1    = (const float*)d_in[11];
  const float* W2    = (const float*)d_in[12];
  const float* b2    = (const float*)d_in[13];
  const float* Wih0  = (const float*)d_in[14];
  const float* Whh0  = (const float*)d_in[15];
  const float* bih0  = (const float*)d_in[16];
  const float* bhh0  = (const float*)d_in[17];
  const float* Wih1  = (const float*)d_in[18];
  const float* Whh1  = (const float*)d_in[19];
  const float* bih1  = (const float*)d_in[20];
  const float* bhh1  = (const float*)d_in[21];

  const int N  = in_sizes[0] / 128;
  const int E  = in_sizes[1] / 2;
  const int EP = E + N;

  float* out      = (float*)d_out;
  float* impacts  = out;
  float* temporal = out + (size_t)3 * N * 3;
  float* hlast    = temporal + (size_t)N * 384;
  float* total    = hlast + (size_t)N * 128;

  // ---- workspace layout ----
  float* ws = (float*)d_ws;
  float* c0 = ws;
  float* c1 = c0 + (size_t)N * 128;
  unsigned short* tempb = (unsigned short*)(c1 + (size_t)N * 128);
  unsigned short* hb0   = tempb + (size_t)N * 384;
  unsigned short* xhb   = hb0 + (size_t)N * 128;
  int* indptr = (int*)(xhb + (size_t)N * 128);
  int* fillc  = indptr + (N + 1);
  int* srcl   = fillc + N;
  int* bsum   = srcl + EP;
  size_t ip = (size_t)((bsum + 256) - (int*)ws);
  ip = (ip + 7) & ~(size_t)7;
  unsigned short* frags = (unsigned short*)((int*)ws + ip);
  unsigned short* WencF = frags;
  unsigned short* WgatF = WencF + 16384;
  unsigned short* W1F   = WgatF + 3 * 16384;
  unsigned short* L0F   = W1F + 3 * 8192;
  unsigned short* L1F   = L0F + 131072;

  float* regA = c1;
  float* aS   = c0;
  float* aD   = c0 + (size_t)N * 4;

  size_t need = ((size_t)N * 128 * 2) * 4 + (size_t)N * 384 * 2 + (size_t)N * 128 * 2 * 2
              + ((size_t)2 * N + 1 + EP + 264) * 4 + (size_t)(16384 * 4 + 8192 * 3 + 131072 * 2) * 2 + 64;
  if (ws_size < need) return;

  const int* esrc = ei;
  const int* edst = ei + E;
  const int rowTiles = (N + 63) / 64;
  const int nscan = (N + 1023) / 1024;

  // ---- build weight fragments ----
  build_frag_kmajor<<<64, 256, 0, stream>>>(Wenc, 128, WencF, 4, 8);
  for (int k = 0; k < 3; ++k) {
    build_frag_kmajor<<<64, 256, 0, stream>>>(Wgat + (size_t)k * 16384, 128, WgatF + (size_t)k * 16384, 4, 8);
    build_frag_kmajor<<<32, 256, 0, stream>>>(W1 + (size_t)k * 8192, 64, W1F + (size_t)k * 8192, 4, 4);
  }
  build_frag_lstm3<<<512, 256, 0, stream>>>(Wih0, Whh0, L0F);
  build_frag_lstm3<<<512, 256, 0, stream>>>(Wih1, Whh1, L1F);

  // ---- CSR by destination, two-level scan ----
  hipMemsetAsync(fillc, 0, (size_t)N * sizeof(int), stream);
  count_kernel<<<(EP + 255) / 256, 256, 0, stream>>>(edst, fillc, E, EP);
  scan1_kernel<<<nscan, 1024, 0, stream>>>(fillc, indptr, bsum, N);
  scan2_kernel<<<1, 64, 0, stream>>>(bsum, indptr, nscan, N);
  scan3_kernel<<<nscan, 1024, 0, stream>>>(indptr, bsum, N);
  hipMemsetAsync(fillc, 0, (size_t)N * sizeof(int), stream);
  fill_kernel<<<(EP + 255) / 256, 256, 0, stream>>>(esrc, edst, indptr, fillc, srcl, E, EP);

  // ---- encoder ----
  gemm_mfma<8, 4, 0, 0, 0, 0><<<dim3(rowTiles, 1), 256, 0, stream>>>(
      x, 128, WencF, 8, c0, nullptr, 128, nullptr, N, nullptr, nullptr, nullptr, nullptr);
  encoder_finish_kernel<<<(N * 128 + 255) / 256, 256, 0, stream>>>(c0, itype, mask, Wenc, benc, hb0, N);

  hipMemsetAsync(total, 0, sizeof(float), stream);

  const int waveGrid = (N * 64 + 255) / 256;

  // ---- 3 GAT hops + impact heads ----
  for (int k = 0; k < 3; ++k) {
    const unsigned short* hinb = (k == 0) ? hb0 : (tempb + (size_t)(k - 1) * 128);
    int ldin = (k == 0) ? 128 : 384;
    gemm_mfma<8, 4, 1, 0, 1, 1><<<dim3(rowTiles, 1), 256, 0, stream>>>(
        hinb, ldin, WgatF + (size_t)k * 16384, 8, nullptr, xhb, 128, nullptr, N,
        attS + k * 128, attD + k * 128, aS, aD);
    gat_fused_kernel<<<waveGrid, 256, 0, stream>>>(xhb, aS, aD, indptr, srcl, bgat + k * 128,
                                                   tempb + (size_t)k * 128, 384, N);
    gemm_mfma<4, 4, 0, 1, 1, 0><<<dim3(rowTiles, 1), 256, 0, stream>>>(
        tempb + (size_t)k * 128, 384, W1F + (size_t)k * 8192, 4,
        regA, nullptr, 64, b1 + k * 64, N, nullptr, nullptr, nullptr, nullptr);
    float wk = ((k == 0) ? 1.f : (k == 1) ? 0.5f : 0.25f) / (3.0f * (float)N);
    impact_out_kernel<<<(N + 255) / 256, 256, 0, stream>>>(regA, W2 + k * 192, b2 + k * 3,
                                                           impacts + (size_t)k * N * 3, total, wk, N);
  }

  // ---- fully fused LSTM (r13 structure + NT streams) ----
  lstm_fused<<<rowTiles, 512, 0, stream>>>(tempb, L0F, L1F, bih0, bhh0, bih1, bhh1,
                                           temporal, hlast, N);
}

// Round 18
// 1646.706 us; speedup vs baseline: 1.1061x; 1.0210x over previous
//
#include <hip/hip_runtime.h>

typedef __attribute__((ext_vector_type(8))) short short8;
typedef __attribute__((ext_vector_type(4))) float f32x4;

__device__ __forceinline__ float4 ld4(const float* p){ return *reinterpret_cast<const float4*>(p); }
__device__ __forceinline__ void st4(float* p, const float4& v){ *reinterpret_cast<float4*>(p) = v; }

__device__ __forceinline__ unsigned short f2b(float x){
  unsigned int u = __float_as_uint(x);
  unsigned int r = (u + 0x7fffu + ((u >> 16) & 1u)) >> 16;
  return (unsigned short)r;
}
__device__ __forceinline__ float b2f(unsigned short b){
  return __uint_as_float(((unsigned int)b) << 16);
}

__device__ __forceinline__ float fsigmoid(float x){ return 1.f / (1.f + __expf(-x)); }
__device__ __forceinline__ float ftanh(float x){ return 1.f - 2.f / (1.f + __expf(2.f * x)); }

__device__ __forceinline__ short8 cvt_frag(float4 f0, float4 f1){
  short8 a;
  a[0]=(short)f2b(f0.x); a[1]=(short)f2b(f0.y); a[2]=(short)f2b(f0.z); a[3]=(short)f2b(f0.w);
  a[4]=(short)f2b(f1.x); a[5]=(short)f2b(f1.y); a[6]=(short)f2b(f1.z); a[7]=(short)f2b(f1.w);
  return a;
}

// ============ weight fragmentization ============
__global__ void build_frag_kmajor(const float* __restrict__ B, int ldb,
                                  unsigned short* __restrict__ BF, int KB, int CTG)
{
  int idx = blockIdx.x * 256 + threadIdx.x;
  int total = KB * CTG * 512;
  if (idx >= total) return;
  int j = idx & 7, lane = (idx >> 3) & 63, rest = idx >> 9;
  int ctg = rest % CTG, kb = rest / CTG;
  int k = kb * 32 + ((lane >> 4) << 3) + j;
  int col = ctg * 16 + (lane & 15);
  BF[idx] = f2b(B[(size_t)k * ldb + col]);
}

// LSTM wave-slice layout (8 waves x 16 j-cols each), round-5 layout
__global__ void build_frag_lstm3(const float* __restrict__ Wih, const float* __restrict__ Whh,
                                 unsigned short* __restrict__ BF)
{
  int idx = blockIdx.x * 256 + threadIdx.x;
  if (idx >= 131072) return;
  int j = idx & 7, lane = (idx >> 3) & 63;
  int g = (idx >> 9) & 3, kb = (idx >> 11) & 7, w = idx >> 14;
  int col = g * 128 + w * 16 + (lane & 15);
  int k = kb * 32 + ((lane >> 4) << 3) + j;
  float v = (k < 128) ? Wih[(size_t)col * 128 + k] : Whh[(size_t)col * 128 + (k - 128)];
  BF[idx] = f2b(v);
}

// ============ generic MFMA GEMM (+optional fused attention logits) ============
template<int CT, int KB, int OUTBF, int RELU, int ABF16, int ATT>
__global__ __launch_bounds__(256)
void gemm_mfma(const void* __restrict__ Av, int lda,
               const unsigned short* __restrict__ BF, int ctgTot,
               float* __restrict__ Cf, unsigned short* __restrict__ Cb, int ldc,
               const float* __restrict__ bias, int nrows,
               const float* __restrict__ attS, const float* __restrict__ attD,
               float* __restrict__ aSo, float* __restrict__ aDo)
{
  const int tid = threadIdx.x, lane = tid & 63, wid = tid >> 6;
  const int row0 = blockIdx.x * 64 + wid * 16;
  const int cg = blockIdx.y * CT;
  const int r = row0 + (lane & 15);
  const bool rok = r < nrows;
  const int koff = (lane >> 4) << 3;
  const int c15 = lane & 15;

  f32x4 acc[CT];
#pragma unroll
  for (int ct = 0; ct < CT; ++ct) {
    float b = bias ? bias[(cg + ct) * 16 + c15] : 0.f;
    acc[ct] = (f32x4){b, b, b, b};
  }

#pragma unroll
  for (int kb = 0; kb < KB; ++kb) {
    short8 a = {};
    if (rok) {
      if (ABF16) {
        a = *(const short8*)((const unsigned short*)Av + (size_t)r * lda + kb * 32 + koff);
      } else {
        const float* p = (const float*)Av + (size_t)r * lda + kb * 32 + koff;
        a = cvt_frag(ld4(p), ld4(p + 4));
      }
    }
#pragma unroll
    for (int ct = 0; ct < CT; ++ct) {
      const short8 b = *(const short8*)(BF + ((size_t)(kb * ctgTot + cg + ct) * 64 + lane) * 8);
      acc[ct] = __builtin_amdgcn_mfma_f32_16x16x32_bf16(a, b, acc[ct], 0, 0, 0);
    }
  }

  const int orow = row0 + ((lane >> 4) << 2);
#pragma unroll
  for (int ct = 0; ct < CT; ++ct) {
    int col = (cg + ct) * 16 + c15;
#pragma unroll
    for (int rg = 0; rg < 4; ++rg) {
      int rr = orow + rg;
      if (rr >= nrows) continue;
      float v = acc[ct][rg];
      if (RELU) v = fmaxf(v, 0.f);
      if (OUTBF) Cb[(size_t)rr * ldc + col] = f2b(v);
      else       Cf[(size_t)rr * ldc + col] = v;
    }
  }

  if (ATT) {
    float s0c[4], s1c[4], d0c[4], d1c[4];
#pragma unroll
    for (int h = 0; h < 4; ++h) {
      s0c[h] = attS[h * 32 + c15];
      s1c[h] = attS[h * 32 + 16 + c15];
      d0c[h] = attD[h * 32 + c15];
      d1c[h] = attD[h * 32 + 16 + c15];
    }
    f32x4 pS[4], pD[4];
#pragma unroll
    for (int h = 0; h < 4; ++h) {
#pragma unroll
      for (int rg = 0; rg < 4; ++rg) {
        pS[h][rg] = acc[2 * h][rg] * s0c[h] + acc[2 * h + 1][rg] * s1c[h];
        pD[h][rg] = acc[2 * h][rg] * d0c[h] + acc[2 * h + 1][rg] * d1c[h];
      }
    }
#pragma unroll
    for (int off = 1; off < 16; off <<= 1) {
#pragma unroll
      for (int h = 0; h < 4; ++h) {
#pragma unroll
        for (int rg = 0; rg < 4; ++rg) {
          pS[h][rg] += __shfl_xor(pS[h][rg], off);
          pD[h][rg] += __shfl_xor(pD[h][rg], off);
        }
      }
    }
    if (c15 == 0) {
#pragma unroll
      for (int rg = 0; rg < 4; ++rg) {
        int rr = orow + rg;
        if (rr < nrows) {
          st4(aSo + (size_t)rr * 4, make_float4(pS[0][rg], pS[1][rg], pS[2][rg], pS[3][rg]));
          st4(aDo + (size_t)rr * 4, make_float4(pD[0][rg], pD[1][rg], pD[2][rg], pD[3][rg]));
        }
      }
    }
  }
}

// ============ fully fused 2-layer x T=3 LSTM (r13 best: plain cached accesses) ============
__global__ __launch_bounds__(512, 2)
void lstm_fused(const unsigned short* __restrict__ tempb,
                const unsigned short* __restrict__ L0F, const unsigned short* __restrict__ L1F,
                const float* __restrict__ bih0, const float* __restrict__ bhh0,
                const float* __restrict__ bih1, const float* __restrict__ bhh1,
                float* __restrict__ temporal, float* __restrict__ hlast, int nrows)
{
  __shared__ unsigned short h0b[8192];
  __shared__ unsigned short h1b[8192];
  __shared__ float h1f[64 * 132];
  const int tid = threadIdx.x, lane = tid & 63, w = tid >> 6;
  const int row0 = blockIdx.x * 64;
  const int rbase = lane & 15;
  const int koff = (lane >> 4) << 3;
  const int c15 = lane & 15;
  const int jw = w * 16;

  float bs0[4], bs1[4];
#pragma unroll
  for (int g = 0; g < 4; ++g) {
    int col = g * 128 + jw + c15;
    bs0[g] = bih0[col] + bhh0[col];
    bs1[g] = bih1[col] + bhh1[col];
  }

  f32x4 c0[4], c1[4];
#pragma unroll
  for (int i = 0; i < 4; ++i) { c0[i] = (f32x4){0,0,0,0}; c1[i] = (f32x4){0,0,0,0}; }

  const unsigned short* BF0 = L0F + (size_t)w * 16384;
  const unsigned short* BF1 = L1F + (size_t)w * 16384;

  f32x4 acc[4][4];

  for (int t = 0; t < 3; ++t) {
    // ---------- layer 0 ----------
#pragma unroll
    for (int rf = 0; rf < 4; ++rf)
#pragma unroll
      for (int g = 0; g < 4; ++g) acc[rf][g] = (f32x4){bs0[g], bs0[g], bs0[g], bs0[g]};

#pragma unroll
    for (int kb = 0; kb < 4; ++kb) {
      short8 a[4];
#pragma unroll
      for (int rf = 0; rf < 4; ++rf) {
        int r = row0 + rf * 16 + rbase;
        a[rf] = (r < nrows) ? *(const short8*)(tempb + (size_t)r * 384 + t * 128 + kb * 32 + koff)
                            : (short8){0,0,0,0,0,0,0,0};
      }
#pragma unroll
      for (int g = 0; g < 4; ++g) {
        const short8 b = *(const short8*)(BF0 + (((size_t)kb * 4 + g) * 64 + lane) * 8);
#pragma unroll
        for (int rf = 0; rf < 4; ++rf)
          acc[rf][g] = __builtin_amdgcn_mfma_f32_16x16x32_bf16(a[rf], b, acc[rf][g], 0, 0, 0);
      }
    }
    if (t > 0) {
#pragma unroll
      for (int kb = 4; kb < 8; ++kb) {
        short8 a[4];
#pragma unroll
        for (int rf = 0; rf < 4; ++rf) {
          int rl = rf * 16 + rbase;
          int kk = (kb - 4) * 32 + koff;
          a[rf] = *(const short8*)(h0b + rl * 128 + (kk ^ ((rl & 7) << 3)));
        }
#pragma unroll
        for (int g = 0; g < 4; ++g) {
          const short8 b = *(const short8*)(BF0 + (((size_t)kb * 4 + g) * 64 + lane) * 8);
#pragma unroll
          for (int rf = 0; rf < 4; ++rf)
            acc[rf][g] = __builtin_amdgcn_mfma_f32_16x16x32_bf16(a[rf], b, acc[rf][g], 0, 0, 0);
        }
      }
    }

    __syncthreads();  // A

#pragma unroll
    for (int rf = 0; rf < 4; ++rf) {
      int j = jw + c15;
#pragma unroll
      for (int rg = 0; rg < 4; ++rg) {
        float si = fsigmoid(acc[rf][0][rg]);
        float sf = fsigmoid(acc[rf][1][rg]);
        float gg = ftanh(acc[rf][2][rg]);
        float so = fsigmoid(acc[rf][3][rg]);
        float c = sf * c0[rf][rg] + si * gg;
        c0[rf][rg] = c;
        float hh = so * ftanh(c);
        int rl = rf * 16 + ((lane >> 4) << 2) + rg;
        h0b[rl * 128 + (j ^ ((rl & 7) << 3))] = f2b(hh);
      }
    }

    __syncthreads();  // B

    // ---------- layer 1 ----------
#pragma unroll
    for (int rf = 0; rf < 4; ++rf)
#pragma unroll
      for (int g = 0; g < 4; ++g) acc[rf][g] = (f32x4){bs1[g], bs1[g], bs1[g], bs1[g]};

#pragma unroll
    for (int kb = 0; kb < 4; ++kb) {
      short8 a[4];
#pragma unroll
      for (int rf = 0; rf < 4; ++rf) {
        int rl = rf * 16 + rbase;
        int kk = kb * 32 + koff;
        a[rf] = *(const short8*)(h0b + rl * 128 + (kk ^ ((rl & 7) << 3)));
      }
#pragma unroll
      for (int g = 0; g < 4; ++g) {
        const short8 b = *(const short8*)(BF1 + (((size_t)kb * 4 + g) * 64 + lane) * 8);
#pragma unroll
        for (int rf = 0; rf < 4; ++rf)
          acc[rf][g] = __builtin_amdgcn_mfma_f32_16x16x32_bf16(a[rf], b, acc[rf][g], 0, 0, 0);
      }
    }
    if (t > 0) {
#pragma unroll
      for (int kb = 4; kb < 8; ++kb) {
        short8 a[4];
#pragma unroll
        for (int rf = 0; rf < 4; ++rf) {
          int rl = rf * 16 + rbase;
          int kk = (kb - 4) * 32 + koff;
          a[rf] = *(const short8*)(h1b + rl * 128 + (kk ^ ((rl & 7) << 3)));
        }
#pragma unroll
        for (int g = 0; g < 4; ++g) {
          const short8 b = *(const short8*)(BF1 + (((size_t)kb * 4 + g) * 64 + lane) * 8);
#pragma unroll
          for (int rf = 0; rf < 4; ++rf)
            acc[rf][g] = __builtin_amdgcn_mfma_f32_16x16x32_bf16(a[rf], b, acc[rf][g], 0, 0, 0);
        }
      }
    }

    __syncthreads();  // C

#pragma unroll
    for (int rf = 0; rf < 4; ++rf) {
      int j = jw + c15;
#pragma unroll
      for (int rg = 0; rg < 4; ++rg) {
        float si = fsigmoid(acc[rf][0][rg]);
        float sf = fsigmoid(acc[rf][1][rg]);
        float gg = ftanh(acc[rf][2][rg]);
        float so = fsigmoid(acc[rf][3][rg]);
        float c = sf * c1[rf][rg] + si * gg;
        c1[rf][rg] = c;
        float hh = so * ftanh(c);
        int rl = rf * 16 + ((lane >> 4) << 2) + rg;
        h1b[rl * 128 + (j ^ ((rl & 7) << 3))] = f2b(hh);
        h1f[rl * 132 + j] = hh;
      }
    }

    __syncthreads();  // D

#pragma unroll
    for (int k = 0; k < 4; ++k) {
      int idx = tid + k * 512;
      int row = idx >> 5;
      int c4 = (idx & 31) << 2;
      int r = row0 + row;
      if (r < nrows) {
        float4 v = ld4(&h1f[row * 132 + c4]);
        st4(&temporal[(size_t)r * 384 + t * 128 + c4], v);
        if (t == 2) st4(&hlast[(size_t)r * 128 + c4], v);
      }
    }
  }
}

// ============ encoder tail ============
__global__ void encoder_finish_kernel(const float* __restrict__ pre, const float* __restrict__ itype,
                                      const float* __restrict__ mask, const float* __restrict__ Wenc,
                                      const float* __restrict__ benc, unsigned short* __restrict__ hb, int n)
{
  int idx = blockIdx.x * blockDim.x + threadIdx.x;
  if (idx >= n * 128) return;
  int nn = idx >> 7, j = idx & 127;
  float v = pre[idx]
          + itype[nn * 3 + 0] * Wenc[128 * 128 + j]
          + itype[nn * 3 + 1] * Wenc[129 * 128 + j]
          + itype[nn * 3 + 2] * Wenc[130 * 128 + j]
          + benc[j];
  hb[idx] = f2b(fmaxf(v, 0.f) * mask[nn]);
}

// ============ CSR build ============
__global__ void count_kernel(const int* __restrict__ dst, int* __restrict__ cnt, int E, int EP)
{
  int e = blockIdx.x * blockDim.x + threadIdx.x;
  if (e >= EP) return;
  int d = (e < E) ? dst[e] : (e - E);
  atomicAdd(&cnt[d], 1);
}

__global__ __launch_bounds__(1024)
void scan1_kernel(const int* __restrict__ cnt, int* __restrict__ indptr,
                  int* __restrict__ bsum, int n)
{
  __shared__ int wsum[16];
  int tid = threadIdx.x;
  int lane = tid & 63, wv = tid >> 6;
  int idx = blockIdx.x * 1024 + tid;
  int v = (idx < n) ? cnt[idx] : 0;
  int x = v;
#pragma unroll
  for (int off = 1; off < 64; off <<= 1) { int y = __shfl_up(x, off); if (lane >= off) x += y; }
  if (lane == 63) wsum[wv] = x;
  __syncthreads();
  if (wv == 0) {
    int t = (lane < 16) ? wsum[lane] : 0;
#pragma unroll
    for (int off = 1; off < 16; off <<= 1) { int y = __shfl_up(t, off); if (lane >= off) t += y; }
    if (lane < 16) wsum[lane] = t;
  }
  __syncthreads();
  int offs = wv ? wsum[wv - 1] : 0;
  if (idx < n) indptr[idx] = offs + x - v;
  if (tid == 0) bsum[blockIdx.x] = wsum[15];
}

__global__ void scan2_kernel(int* __restrict__ bsum, int* __restrict__ indptr, int nb, int n)
{
  if (threadIdx.x == 0 && blockIdx.x == 0) {
    int run = 0;
    for (int i = 0; i < nb; ++i) { int t = bsum[i]; bsum[i] = run; run += t; }
    indptr[n] = run;
  }
}

__global__ __launch_bounds__(1024)
void scan3_kernel(int* __restrict__ indptr, const int* __restrict__ bsum, int n)
{
  int idx = blockIdx.x * 1024 + threadIdx.x;
  if (idx < n) indptr[idx] += bsum[blockIdx.x];
}

__global__ void fill_kernel(const int* __restrict__ src, const int* __restrict__ dst,
                            const int* __restrict__ indptr, int* __restrict__ fillc,
                            int* __restrict__ srcl, int E, int EP)
{
  int e = blockIdx.x * blockDim.x + threadIdx.x;
  if (e >= EP) return;
  int d, s;
  if (e < E) { d = dst[e]; s = src[e]; } else { d = e - E; s = e - E; }
  int pos = atomicAdd(&fillc[d], 1);
  srcl[indptr[d] + pos] = s;
}

// ============ GAT: fused softmax + weighted gather — no max pass (shift-invariant) ============
__global__ __launch_bounds__(256)
void gat_fused_kernel(const unsigned short* __restrict__ xhb,
                      const float* __restrict__ aS, const float* __restrict__ aD,
                      const int* __restrict__ indptr, const int* __restrict__ srcl,
                      const float* __restrict__ bgat, unsigned short* __restrict__ outb,
                      int ldo, int n)
{
  int wid = (int)((blockIdx.x * (size_t)blockDim.x + threadIdx.x) >> 6);
  int lane = threadIdx.x & 63;
  if (wid >= n) return;
  int eb = indptr[wid], ee = indptr[wid + 1];
  int hsel = lane >> 4;
  float adh = aD[wid * 4 + hsel];
  float sum = 0.f, acc0 = 0.f, acc1 = 0.f;
  int i = eb;
  for (; i + 1 < ee; i += 2) {
    int s0 = srcl[i], s1 = srcl[i + 1];
    float e0 = aS[s0 * 4 + hsel] + adh; e0 = e0 > 0.f ? e0 : 0.2f * e0;
    float e1 = aS[s1 * 4 + hsel] + adh; e1 = e1 > 0.f ? e1 : 0.2f * e1;
    unsigned int px0 = *(const unsigned int*)(xhb + (size_t)s0 * 128 + lane * 2);
    unsigned int px1 = *(const unsigned int*)(xhb + (size_t)s1 * 128 + lane * 2);
    float p0 = __expf(e0);
    float p1 = __expf(e1);
    sum += p0 + p1;
    acc0 = fmaf(p0, b2f((unsigned short)(px0 & 0xffff)), acc0);
    acc1 = fmaf(p0, b2f((unsigned short)(px0 >> 16)), acc1);
    acc0 = fmaf(p1, b2f((unsigned short)(px1 & 0xffff)), acc0);
    acc1 = fmaf(p1, b2f((unsigned short)(px1 >> 16)), acc1);
  }
  if (i < ee) {
    int s = srcl[i];
    float e = aS[s * 4 + hsel] + adh; e = e > 0.f ? e : 0.2f * e;
    float p = __expf(e);
    sum += p;
    unsigned int px = *(const unsigned int*)(xhb + (size_t)s * 128 + lane * 2);
    acc0 = fmaf(p, b2f((unsigned short)(px & 0xffff)), acc0);
    acc1 = fmaf(p, b2f((unsigned short)(px >> 16)), acc1);
  }
  float dv = 1.f / (sum + 1e-16f);
  float ox = acc0 * dv + bgat[lane * 2];
  float oy = acc1 * dv + bgat[lane * 2 + 1];
  unsigned int pk = (unsigned int)f2b(ox) | ((unsigned int)f2b(oy) << 16);
  *reinterpret_cast<unsigned int*>(outb + (size_t)wid * ldo + lane * 2) = pk;
}

// ============ impact head layer 2 + |.| mean ============
__global__ __launch_bounds__(256)
void impact_out_kernel(const float* __restrict__ hid, const float* __restrict__ W2,
                       const float* __restrict__ b2, float* __restrict__ outp,
                       float* __restrict__ total, float wk, int n)
{
  __shared__ float red[256];
  int idx = blockIdx.x * 256 + threadIdx.x;
  float part = 0.f;
  if (idx < n) {
    const float* h = hid + (size_t)idx * 64;
    float o0 = b2[0], o1 = b2[1], o2 = b2[2];
#pragma unroll 8
    for (int k = 0; k < 64; ++k) {
      float v = h[k];
      o0 = fmaf(v, W2[k * 3 + 0], o0);
      o1 = fmaf(v, W2[k * 3 + 1], o1);
      o2 = fmaf(v, W2[k * 3 + 2], o2);
    }
    outp[(size_t)idx * 3 + 0] = o0;
    outp[(size_t)idx * 3 + 1] = o1;
    outp[(size_t)idx * 3 + 2] = o2;
    part = fabsf(o0) + fabsf(o1) + fabsf(o2);
  }
  red[threadIdx.x] = part;
  __syncthreads();
  for (int s = 128; s; s >>= 1) {
    if (threadIdx.x < s) red[threadIdx.x] += red[threadIdx.x + s];
    __syncthreads();
  }
  if (threadIdx.x == 0) atomicAdd(total, red[0] * wk);
}

// ============ host ============
extern "C" void kernel_launch(void* const* d_in, const int* in_sizes, int n_in,
                              void* d_out, int out_size, void* d_ws, size_t ws_size,
                              hipStream_t stream)
{
  const float* x     = (const float*)d_in[0];
  const int*   ei    = (const int*)  d_in[1];
  const float* mask  = (const float*)d_in[2];
  const float* itype = (const float*)d_in[3];
  const float* Wenc  = (const float*)d_in[4];
  const float* benc  = (const float*)d_in[5];
  const float* Wgat  = (const float*)d_in[6];
  const float* attS  = (const float*)d_in[7];
  const float* attD  = (const float*)d_in[8];
  const float* bgat  = (const float*)d_in[9];
  const float* W1    = (const float*)d_in[10];
  const float* b1    = (const float*)d_in[11];
  const float* W2    = (const float*)d_in[12];
  const float* b2    = (const float*)d_in[13];
  const float* Wih0  = (const float*)d_in[14];
  const float* Whh0  = (const float*)d_in[15];
  const float* bih0  = (const float*)d_in[16];
  const float* bhh0  = (const float*)d_in[17];
  const float* Wih1  = (const float*)d_in[18];
  const float* Whh1  = (const float*)d_in[19];
  const float* bih1  = (const float*)d_in[20];
  const float* bhh1  = (const float*)d_in[21];

  const int N  = in_sizes[0] / 128;
  const int E  = in_sizes[1] / 2;
  const int EP = E + N;

  float* out      = (float*)d_out;
  float* impacts  = out;
  float* temporal = out + (size_t)3 * N * 3;
  float* hlast    = temporal + (size_t)N * 384;
  float* total    = hlast + (size_t)N * 128;

  // ---- workspace layout ----
  float* ws = (float*)d_ws;
  float* c0 = ws;
  float* c1 = c0 + (size_t)N * 128;
  unsigned short* tempb = (unsigned short*)(c1 + (size_t)N * 128);
  unsigned short* hb0   = tempb + (size_t)N * 384;
  unsigned short* xhb   = hb0 + (size_t)N * 128;
  int* indptr = (int*)(xhb + (size_t)N * 128);
  int* fillc  = indptr + (N + 1);
  int* srcl   = fillc + N;
  int* bsum   = srcl + EP;
  size_t ip = (size_t)((bsum + 256) - (int*)ws);
  ip = (ip + 7) & ~(size_t)7;
  unsigned short* frags = (unsigned short*)((int*)ws + ip);
  unsigned short* WencF = frags;
  unsigned short* WgatF = WencF + 16384;
  unsigned short* W1F   = WgatF + 3 * 16384;
  unsigned short* L0F   = W1F + 3 * 8192;
  unsigned short* L1F   = L0F + 131072;

  float* regA = c1;
  float* aS   = c0;
  float* aD   = c0 + (size_t)N * 4;

  size_t need = ((size_t)N * 128 * 2) * 4 + (size_t)N * 384 * 2 + (size_t)N * 128 * 2 * 2
              + ((size_t)2 * N + 1 + EP + 264) * 4 + (size_t)(16384 * 4 + 8192 * 3 + 131072 * 2) * 2 + 64;
  if (ws_size < need) return;

  const int* esrc = ei;
  const int* edst = ei + E;
  const int rowTiles = (N + 63) / 64;
  const int nscan = (N + 1023) / 1024;

  // ---- build weight fragments ----
  build_frag_kmajor<<<64, 256, 0, stream>>>(Wenc, 128, WencF, 4, 8);
  for (int k = 0; k < 3; ++k) {
    build_frag_kmajor<<<64, 256, 0, stream>>>(Wgat + (size_t)k * 16384, 128, WgatF + (size_t)k * 16384, 4, 8);
    build_frag_kmajor<<<32, 256, 0, stream>>>(W1 + (size_t)k * 8192, 64, W1F + (size_t)k * 8192, 4, 4);
  }
  build_frag_lstm3<<<512, 256, 0, stream>>>(Wih0, Whh0, L0F);
  build_frag_lstm3<<<512, 256, 0, stream>>>(Wih1, Whh1, L1F);

  // ---- CSR by destination, two-level scan ----
  hipMemsetAsync(fillc, 0, (size_t)N * sizeof(int), stream);
  count_kernel<<<(EP + 255) / 256, 256, 0, stream>>>(edst, fillc, E, EP);
  scan1_kernel<<<nscan, 1024, 0, stream>>>(fillc, indptr, bsum, N);
  scan2_kernel<<<1, 64, 0, stream>>>(bsum, indptr, nscan, N);
  scan3_kernel<<<nscan, 1024, 0, stream>>>(indptr, bsum, N);
  hipMemsetAsync(fillc, 0, (size_t)N * sizeof(int), stream);
  fill_kernel<<<(EP + 255) / 256, 256, 0, stream>>>(esrc, edst, indptr, fillc, srcl, E, EP);

  // ---- encoder ----
  gemm_mfma<8, 4, 0, 0, 0, 0><<<dim3(rowTiles, 1), 256, 0, stream>>>(
      x, 128, WencF, 8, c0, nullptr, 128, nullptr, N, nullptr, nullptr, nullptr, nullptr);
  encoder_finish_kernel<<<(N * 128 + 255) / 256, 256, 0, stream>>>(c0, itype, mask, Wenc, benc, hb0, N);

  hipMemsetAsync(total, 0, sizeof(float), stream);

  const int waveGrid = (N * 64 + 255) / 256;

  // ---- 3 GAT hops + impact heads ----
  for (int k = 0; k < 3; ++k) {
    const unsigned short* hinb = (k == 0) ? hb0 : (tempb + (size_t)(k - 1) * 128);
    int ldin = (k == 0) ? 128 : 384;
    gemm_mfma<8, 4, 1, 0, 1, 1><<<dim3(rowTiles, 1), 256, 0, stream>>>(
        hinb, ldin, WgatF + (size_t)k * 16384, 8, nullptr, xhb, 128, nullptr, N,
        attS + k * 128, attD + k * 128, aS, aD);
    gat_fused_kernel<<<waveGrid, 256, 0, stream>>>(xhb, aS, aD, indptr, srcl, bgat + k * 128,
                                                   tempb + (size_t)k * 128, 384, N);
    gemm_mfma<4, 4, 0, 1, 1, 0><<<dim3(rowTiles, 1), 256, 0, stream>>>(
        tempb + (size_t)k * 128, 384, W1F + (size_t)k * 8192, 4,
        regA, nullptr, 64, b1 + k * 64, N, nullptr, nullptr, nullptr, nullptr);
    float wk = ((k == 0) ? 1.f : (k == 1) ? 0.5f : 0.25f) / (3.0f * (float)N);
    impact_out_kernel<<<(N + 255) / 256, 256, 0, stream>>>(regA, W2 + k * 192, b2 + k * 3,
                                                           impacts + (size_t)k * N * 3, total, wk, N);
  }

  // ---- fully fused LSTM (r13 best structure, plain cached accesses) ----
  lstm_fused<<<rowTiles, 512, 0, stream>>>(tempb, L0F, L1F, bih0, bhh0, bih1, bhh1,
                                           temporal, hlast, N);
}